// Round 1
// baseline (5111.720 us; speedup 1.0000x reference)
//
#include <hip/hip_runtime.h>
#include <math.h>

#define HH    256
#define NHEAD 8
#define HD    32
#define CC    128
#define RR    24
#define PP    276
#define NBLK  2
#define DFF   1024
#define MTOK  (PP*CC)   // 35328

__device__ __forceinline__ float gelu_f(float x) {
    return 0.5f * x * (1.0f + erff(x * 0.7071067811865476f));
}

// ---------------------------------------------------------------------------
// h[p,c,:] = sum_r pm[p,r] * emb[x[r,c]]   (pm rows have two 1.0 entries)
// grid (PP, CC), block 256 (one thread per H element)
// ---------------------------------------------------------------------------
__global__ __launch_bounds__(256) void k_embed(
    const int* __restrict__ x, const float* __restrict__ pm,
    const float* __restrict__ emb, float* __restrict__ h) {
    const int p = blockIdx.x, c = blockIdx.y, t = threadIdx.x;
    float acc = 0.f;
    for (int r = 0; r < RR; ++r) {
        float w = pm[p * RR + r];          // uniform across block -> no divergence
        if (w != 0.f) {
            int tok = x[r * CC + c];
            acc += w * emb[(size_t)tok * HH + t];
        }
    }
    h[((size_t)p * CC + c) * HH + t] = acc;
}

// ---------------------------------------------------------------------------
// LayerNorm over H=256 per token. One block (256 thr) per token row.
// ---------------------------------------------------------------------------
__global__ __launch_bounds__(256) void k_ln(
    const float* __restrict__ in, float* __restrict__ out,
    const float* __restrict__ g, const float* __restrict__ b) {
    const int row = blockIdx.x, t = threadIdx.x;
    const float xv = in[(size_t)row * HH + t];
    float s = xv, s2 = xv * xv;
    #pragma unroll
    for (int off = 32; off; off >>= 1) {
        s  += __shfl_down(s,  off);
        s2 += __shfl_down(s2, off);
    }
    __shared__ float sm[8];
    const int lane = t & 63, wid = t >> 6;
    if (lane == 0) { sm[wid] = s; sm[wid + 4] = s2; }
    __syncthreads();
    const float ssum  = sm[0] + sm[1] + sm[2] + sm[3];
    const float s2sum = sm[4] + sm[5] + sm[6] + sm[7];
    const float mean = ssum * (1.f / HH);
    const float var  = s2sum * (1.f / HH) - mean * mean;
    const float inv  = rsqrtf(var + 1e-5f);
    out[(size_t)row * HH + t] = (xv - mean) * inv * g[t] + b[t];
}

// ---------------------------------------------------------------------------
// Tiled f32 GEMM: C = [C +] act(A[M,K] @ W[K,N] [+ bias])
// 64x64 tile, 256 threads, 4x4 micro-tile. M%64==0, N%64==0, K%16==0.
// ---------------------------------------------------------------------------
template<bool BIAS, bool GELU, bool RES>
__global__ __launch_bounds__(256) void k_gemm(
    const float* __restrict__ A, const float* __restrict__ W,
    const float* __restrict__ bias, float* __restrict__ C,
    int M, int N, int K) {
    __shared__ float As[16][65];
    __shared__ float Ws[16][65];
    const int tid = threadIdx.x;
    const int tx = tid & 15, ty = tid >> 4;
    const int row0 = blockIdx.x * 64, col0 = blockIdx.y * 64;
    float acc[4][4] = {};
    for (int kt = 0; kt < K; kt += 16) {
        #pragma unroll
        for (int i = 0; i < 4; ++i) {
            int idx = tid + i * 256;            // 0..1023
            int m  = idx >> 4, kk = idx & 15;
            As[kk][m] = A[(size_t)(row0 + m) * K + kt + kk];
            int kk2 = idx >> 6, n = idx & 63;
            Ws[kk2][n] = W[(size_t)(kt + kk2) * N + col0 + n];
        }
        __syncthreads();
        #pragma unroll
        for (int kk = 0; kk < 16; ++kk) {
            float a0[4], b0[4];
            #pragma unroll
            for (int i = 0; i < 4; ++i) a0[i] = As[kk][ty * 4 + i];
            #pragma unroll
            for (int i = 0; i < 4; ++i) b0[i] = Ws[kk][tx * 4 + i];
            #pragma unroll
            for (int i = 0; i < 4; ++i)
                #pragma unroll
                for (int j = 0; j < 4; ++j) acc[i][j] += a0[i] * b0[j];
        }
        __syncthreads();
    }
    #pragma unroll
    for (int i = 0; i < 4; ++i) {
        const int r = row0 + ty * 4 + i;
        #pragma unroll
        for (int j = 0; j < 4; ++j) {
            const int cix = col0 + tx * 4 + j;
            float v = acc[i][j];
            if (BIAS) v += bias[cix];
            if (GELU) v = gelu_f(v);
            if (RES) C[(size_t)r * N + cix] += v;
            else     C[(size_t)r * N + cix]  = v;
        }
    }
}

// ---------------------------------------------------------------------------
// Attention for one (sequence, head) per block; one thread per query row,
// online softmax, K/V streamed from cache. Token index = base + s*stride.
// Row attn: grid(PP,8), S=CC, base_mul=CC, stride=1
// Col attn: grid(CC,8), S=PP, base_mul=1,  stride=CC
// ---------------------------------------------------------------------------
__global__ __launch_bounds__(128) void k_attn(
    const float* __restrict__ q, const float* __restrict__ k,
    const float* __restrict__ v, float* __restrict__ o,
    int S, int base_mul, int stride) {
    const int seq = blockIdx.x, hd = blockIdx.y;
    const int base = seq * base_mul;
    const float scale = 0.17677669529663687f;   // 1/sqrt(32)
    for (int qi = threadIdx.x; qi < S; qi += 128) {
        const float* qr = q + ((size_t)(base + qi * stride)) * HH + hd * HD;
        float qv[HD];
        #pragma unroll
        for (int d = 0; d < HD; ++d) qv[d] = qr[d];
        float m = -1e30f, l = 0.f;
        float acc[HD];
        #pragma unroll
        for (int d = 0; d < HD; ++d) acc[d] = 0.f;
        for (int s = 0; s < S; ++s) {
            const size_t toff = ((size_t)(base + s * stride)) * HH + hd * HD;
            const float* kr = k + toff;
            float dot = 0.f;
            #pragma unroll
            for (int d = 0; d < HD; ++d) dot += qv[d] * kr[d];
            dot *= scale;
            const float mn   = fmaxf(m, dot);
            const float pe   = expf(dot - mn);
            const float corr = expf(m - mn);
            const float* vr = v + toff;
            l = l * corr + pe;
            #pragma unroll
            for (int d = 0; d < HD; ++d) acc[d] = acc[d] * corr + pe * vr[d];
            m = mn;
        }
        const float inv = 1.f / l;
        float* orow = o + ((size_t)(base + qi * stride)) * HH + hd * HD;
        #pragma unroll
        for (int d = 0; d < HD; ++d) orow[d] = acc[d] * inv;
    }
}

// ---------------------------------------------------------------------------
// y[tok] = sum_f g[tok,f]*pw2[f] + pb2
// ---------------------------------------------------------------------------
__global__ __launch_bounds__(256) void k_head1(
    const float* __restrict__ g, const float* __restrict__ pw2,
    const float* __restrict__ pb2, float* __restrict__ y) {
    const int tok = blockIdx.x, t = threadIdx.x;
    const float* row = g + (size_t)tok * DFF;
    float s = 0.f;
    for (int f = t; f < DFF; f += 256) s += row[f] * pw2[f];
    #pragma unroll
    for (int off = 32; off; off >>= 1) s += __shfl_down(s, off);
    __shared__ float sm[4];
    if ((t & 63) == 0) sm[t >> 6] = s;
    __syncthreads();
    if (t == 0) y[tok] = sm[0] + sm[1] + sm[2] + sm[3] + pb2[0];
}

// ---------------------------------------------------------------------------
// out[p] = sum_c y[p,c]*uw[c] + ub
// ---------------------------------------------------------------------------
__global__ __launch_bounds__(128) void k_head2(
    const float* __restrict__ y, const float* __restrict__ uw,
    const float* __restrict__ ub, float* __restrict__ out) {
    const int p = blockIdx.x, t = threadIdx.x;
    float s = y[(size_t)p * CC + t] * uw[t];
    #pragma unroll
    for (int off = 32; off; off >>= 1) s += __shfl_down(s, off);
    __shared__ float sm[2];
    if ((t & 63) == 0) sm[t >> 6] = s;
    __syncthreads();
    if (t == 0) out[p] = sm[0] + sm[1] + ub[0];
}

// ---------------------------------------------------------------------------
extern "C" void kernel_launch(void* const* d_in, const int* in_sizes, int n_in,
                              void* d_out, int out_size, void* d_ws, size_t ws_size,
                              hipStream_t stream) {
    (void)in_sizes; (void)n_in; (void)out_size; (void)ws_size;
    const int*   x    = (const int*)  d_in[0];
    const float* pm   = (const float*)d_in[1];
    const float* emb  = (const float*)d_in[2];
    const float* ln1g = (const float*)d_in[3];
    const float* ln1b = (const float*)d_in[4];
    const float* wqr  = (const float*)d_in[5];
    const float* wkr  = (const float*)d_in[6];
    const float* wvr  = (const float*)d_in[7];
    const float* wor  = (const float*)d_in[8];
    const float* ln2g = (const float*)d_in[9];
    const float* ln2b = (const float*)d_in[10];
    const float* wqc  = (const float*)d_in[11];
    const float* wkc  = (const float*)d_in[12];
    const float* wvc  = (const float*)d_in[13];
    const float* woc  = (const float*)d_in[14];
    const float* ln3g = (const float*)d_in[15];
    const float* ln3b = (const float*)d_in[16];
    const float* fw1  = (const float*)d_in[17];
    const float* fb1  = (const float*)d_in[18];
    const float* fw2  = (const float*)d_in[19];
    const float* fb2  = (const float*)d_in[20];
    const float* pw1  = (const float*)d_in[21];
    const float* pb1  = (const float*)d_in[22];
    const float* pw2  = (const float*)d_in[23];
    const float* pb2  = (const float*)d_in[24];
    const float* uw   = (const float*)d_in[25];
    const float* ub   = (const float*)d_in[26];
    float* out = (float*)d_out;

    // workspace layout (f32): [h 36.2MB][z 36.2MB][big 144.7MB][y 141KB]
    float* h   = (float*)d_ws;
    float* z   = h + (size_t)MTOK * HH;
    float* big = z + (size_t)MTOK * HH;
    float* qb  = big;
    float* kb  = big + (size_t)MTOK * HH;
    float* vb  = big + 2 * (size_t)MTOK * HH;
    float* yb  = big + (size_t)MTOK * DFF;

    const dim3 gP (MTOK / 64, HH  / 64);   // proj GEMMs  (N=256)
    const dim3 gF1(MTOK / 64, DFF / 64);   // up GEMMs    (N=1024)

    k_embed<<<dim3(PP, CC), 256, 0, stream>>>(x, pm, emb, h);

    for (int i = 0; i < NBLK; ++i) {
        const size_t wo2 = (size_t)i * HH * HH;
        // ---- row attention (along C) ----
        k_ln<<<MTOK, 256, 0, stream>>>(h, z, ln1g + i * HH, ln1b + i * HH);
        k_gemm<false,false,false><<<gP, 256, 0, stream>>>(z, wqr + wo2, nullptr, qb, MTOK, HH, HH);
        k_gemm<false,false,false><<<gP, 256, 0, stream>>>(z, wkr + wo2, nullptr, kb, MTOK, HH, HH);
        k_gemm<false,false,false><<<gP, 256, 0, stream>>>(z, wvr + wo2, nullptr, vb, MTOK, HH, HH);
        k_attn<<<dim3(PP, NHEAD), 128, 0, stream>>>(qb, kb, vb, z, CC, CC, 1);
        k_gemm<false,false,true ><<<gP, 256, 0, stream>>>(z, wor + wo2, nullptr, h, MTOK, HH, HH);
        // ---- column attention (along P) ----
        k_ln<<<MTOK, 256, 0, stream>>>(h, z, ln2g + i * HH, ln2b + i * HH);
        k_gemm<false,false,false><<<gP, 256, 0, stream>>>(z, wqc + wo2, nullptr, qb, MTOK, HH, HH);
        k_gemm<false,false,false><<<gP, 256, 0, stream>>>(z, wkc + wo2, nullptr, kb, MTOK, HH, HH);
        k_gemm<false,false,false><<<gP, 256, 0, stream>>>(z, wvc + wo2, nullptr, vb, MTOK, HH, HH);
        k_attn<<<dim3(CC, NHEAD), 128, 0, stream>>>(qb, kb, vb, z, PP, 1, CC);
        k_gemm<false,false,true ><<<gP, 256, 0, stream>>>(z, woc + wo2, nullptr, h, MTOK, HH, HH);
        // ---- feed-forward ----
        k_ln<<<MTOK, 256, 0, stream>>>(h, z, ln3g + i * HH, ln3b + i * HH);
        k_gemm<true ,true ,false><<<gF1, 256, 0, stream>>>(z, fw1 + (size_t)i * HH * DFF, fb1 + i * DFF, big, MTOK, DFF, HH);
        k_gemm<true ,false,true ><<<gP , 256, 0, stream>>>(big, fw2 + (size_t)i * DFF * HH, fb2 + i * HH, h, MTOK, HH, DFF);
    }

    // ---- output head ----
    k_gemm<true,true,false><<<gF1, 256, 0, stream>>>(h, pw1, pb1, big, MTOK, DFF, HH);
    k_head1<<<MTOK, 256, 0, stream>>>(big, pw2, pb2, yb);
    k_head2<<<PP, 128, 0, stream>>>(yb, uw, ub, out);
}

// Round 2
// 4587.289 us; speedup vs baseline: 1.1143x; 1.1143x over previous
//
#include <hip/hip_runtime.h>
#include <math.h>

#define HH    256
#define NHEAD 8
#define HD    32
#define CC    128
#define RR    24
#define PP    276
#define NBLK  2
#define DFF   1024
#define MTOK  (PP*CC)   // 35328
#define CS    64        // attention K/V chunk rows staged in LDS

__device__ __forceinline__ float gelu_f(float x) {
    return 0.5f * x * (1.0f + erff(x * 0.7071067811865476f));
}

// ---------------------------------------------------------------------------
// h[p,c,:] = sum_r pm[p,r] * emb[x[r,c]]
// ---------------------------------------------------------------------------
__global__ __launch_bounds__(256) void k_embed(
    const int* __restrict__ x, const float* __restrict__ pm,
    const float* __restrict__ emb, float* __restrict__ h) {
    const int p = blockIdx.x, c = blockIdx.y, t = threadIdx.x;
    float acc = 0.f;
    for (int r = 0; r < RR; ++r) {
        float w = pm[p * RR + r];
        if (w != 0.f) {
            int tok = x[r * CC + c];
            acc += w * emb[(size_t)tok * HH + t];
        }
    }
    h[((size_t)p * CC + c) * HH + t] = acc;
}

// ---------------------------------------------------------------------------
// LayerNorm over H=256 per token. One block (256 thr) per token row.
// ---------------------------------------------------------------------------
__global__ __launch_bounds__(256) void k_ln(
    const float* __restrict__ in, float* __restrict__ out,
    const float* __restrict__ g, const float* __restrict__ b) {
    const int row = blockIdx.x, t = threadIdx.x;
    const float xv = in[(size_t)row * HH + t];
    float s = xv, s2 = xv * xv;
    #pragma unroll
    for (int off = 32; off; off >>= 1) {
        s  += __shfl_down(s,  off);
        s2 += __shfl_down(s2, off);
    }
    __shared__ float sm[8];
    const int lane = t & 63, wid = t >> 6;
    if (lane == 0) { sm[wid] = s; sm[wid + 4] = s2; }
    __syncthreads();
    const float ssum  = sm[0] + sm[1] + sm[2] + sm[3];
    const float s2sum = sm[4] + sm[5] + sm[6] + sm[7];
    const float mean = ssum * (1.f / HH);
    const float var  = s2sum * (1.f / HH) - mean * mean;
    const float inv  = rsqrtf(var + 1e-5f);
    out[(size_t)row * HH + t] = (xv - mean) * inv * g[t] + b[t];
}

// ---------------------------------------------------------------------------
// Tiled f32 GEMM: C = [C +] act(A[M,K] @ W[K,N] [+ bias])
// ---------------------------------------------------------------------------
template<bool BIAS, bool GELU, bool RES>
__global__ __launch_bounds__(256) void k_gemm(
    const float* __restrict__ A, const float* __restrict__ W,
    const float* __restrict__ bias, float* __restrict__ C,
    int M, int N, int K) {
    __shared__ float As[16][65];
    __shared__ float Ws[16][65];
    const int tid = threadIdx.x;
    const int tx = tid & 15, ty = tid >> 4;
    const int row0 = blockIdx.x * 64, col0 = blockIdx.y * 64;
    float acc[4][4] = {};
    for (int kt = 0; kt < K; kt += 16) {
        #pragma unroll
        for (int i = 0; i < 4; ++i) {
            int idx = tid + i * 256;
            int m  = idx >> 4, kk = idx & 15;
            As[kk][m] = A[(size_t)(row0 + m) * K + kt + kk];
            int kk2 = idx >> 6, n = idx & 63;
            Ws[kk2][n] = W[(size_t)(kt + kk2) * N + col0 + n];
        }
        __syncthreads();
        #pragma unroll
        for (int kk = 0; kk < 16; ++kk) {
            float a0[4], b0[4];
            #pragma unroll
            for (int i = 0; i < 4; ++i) a0[i] = As[kk][ty * 4 + i];
            #pragma unroll
            for (int i = 0; i < 4; ++i) b0[i] = Ws[kk][tx * 4 + i];
            #pragma unroll
            for (int i = 0; i < 4; ++i)
                #pragma unroll
                for (int j = 0; j < 4; ++j) acc[i][j] += a0[i] * b0[j];
        }
        __syncthreads();
    }
    #pragma unroll
    for (int i = 0; i < 4; ++i) {
        const int r = row0 + ty * 4 + i;
        #pragma unroll
        for (int j = 0; j < 4; ++j) {
            const int cix = col0 + tx * 4 + j;
            float v = acc[i][j];
            if (BIAS) v += bias[cix];
            if (GELU) v = gelu_f(v);
            if (RES) C[(size_t)r * N + cix] += v;
            else     C[(size_t)r * N + cix]  = v;
        }
    }
}

// ---------------------------------------------------------------------------
// Attention: one block per (sequence, head). One query per thread (regs),
// K/V staged in LDS in CS-row chunks, online softmax amortized over
// compile-time sub-chunks of 16 scores.
// Row attn: grid(PP,8), block 128, S=CC, base_mul=CC, stride=1
// Col attn: grid(CC,8), block 320, S=PP, base_mul=1,  stride=CC
// ---------------------------------------------------------------------------
__global__ __launch_bounds__(320) void k_attn(
    const float* __restrict__ q, const float* __restrict__ k,
    const float* __restrict__ v, float* __restrict__ o,
    int S, int base_mul, int stride) {
    const int seq = blockIdx.x, hd = blockIdx.y;
    const int base = seq * base_mul;
    const int t = threadIdx.x;
    const int nthr = blockDim.x;
    const float scale = 0.17677669529663687f;   // 1/sqrt(32)

    __shared__ float Ks[CS][HD];
    __shared__ float Vs[CS][HD];

    const int qi = t;
    const bool act = (qi < S);
    float qv[HD], accv[HD];
    float m = -1e30f, l = 0.f;
    if (act) {
        const float* qr = q + ((size_t)(base + qi * stride)) * HH + hd * HD;
        #pragma unroll
        for (int d = 0; d < HD; ++d) { qv[d] = qr[d] * scale; accv[d] = 0.f; }
    }

    for (int s0 = 0; s0 < S; s0 += CS) {
        // cooperative chunk load (float4, zero-padded beyond S)
        for (int idx = t; idx < CS * (HD / 4); idx += nthr) {
            const int r = idx >> 3, d4 = (idx & 7) * 4;
            float4 kv, vv;
            if (s0 + r < S) {
                const size_t toff = ((size_t)(base + (s0 + r) * stride)) * HH + hd * HD + d4;
                kv = *(const float4*)&k[toff];
                vv = *(const float4*)&v[toff];
            } else {
                kv = make_float4(0.f, 0.f, 0.f, 0.f);
                vv = make_float4(0.f, 0.f, 0.f, 0.f);
            }
            *(float4*)&Ks[r][d4] = kv;
            *(float4*)&Vs[r][d4] = vv;
        }
        __syncthreads();
        if (act) {
            #pragma unroll
            for (int ss = 0; ss < CS; ss += 16) {
                float sc[16];
                #pragma unroll
                for (int j = 0; j < 16; ++j) {
                    float dot = 0.f;
                    #pragma unroll
                    for (int d = 0; d < HD; ++d) dot += qv[d] * Ks[ss + j][d];
                    sc[j] = (s0 + ss + j < S) ? dot : -1e30f;
                }
                float mx = m;
                #pragma unroll
                for (int j = 0; j < 16; ++j) mx = fmaxf(mx, sc[j]);
                const float corr = __expf(m - mx);
                m = mx;
                l *= corr;
                #pragma unroll
                for (int d = 0; d < HD; ++d) accv[d] *= corr;
                #pragma unroll
                for (int j = 0; j < 16; ++j) {
                    const float p = __expf(sc[j] - mx);
                    l += p;
                    #pragma unroll
                    for (int d = 0; d < HD; ++d) accv[d] += p * Vs[ss + j][d];
                }
            }
        }
        __syncthreads();
    }

    if (act) {
        const float inv = 1.f / l;
        float* orow = o + ((size_t)(base + qi * stride)) * HH + hd * HD;
        #pragma unroll
        for (int d = 0; d < HD; ++d) orow[d] = accv[d] * inv;
    }
}

// ---------------------------------------------------------------------------
__global__ __launch_bounds__(256) void k_head1(
    const float* __restrict__ g, const float* __restrict__ pw2,
    const float* __restrict__ pb2, float* __restrict__ y) {
    const int tok = blockIdx.x, t = threadIdx.x;
    const float* row = g + (size_t)tok * DFF;
    float s = 0.f;
    for (int f = t; f < DFF; f += 256) s += row[f] * pw2[f];
    #pragma unroll
    for (int off = 32; off; off >>= 1) s += __shfl_down(s, off);
    __shared__ float sm[4];
    if ((t & 63) == 0) sm[t >> 6] = s;
    __syncthreads();
    if (t == 0) y[tok] = sm[0] + sm[1] + sm[2] + sm[3] + pb2[0];
}

__global__ __launch_bounds__(128) void k_head2(
    const float* __restrict__ y, const float* __restrict__ uw,
    const float* __restrict__ ub, float* __restrict__ out) {
    const int p = blockIdx.x, t = threadIdx.x;
    float s = y[(size_t)p * CC + t] * uw[t];
    #pragma unroll
    for (int off = 32; off; off >>= 1) s += __shfl_down(s, off);
    __shared__ float sm[2];
    if ((t & 63) == 0) sm[t >> 6] = s;
    __syncthreads();
    if (t == 0) out[p] = sm[0] + sm[1] + ub[0];
}

// ---------------------------------------------------------------------------
extern "C" void kernel_launch(void* const* d_in, const int* in_sizes, int n_in,
                              void* d_out, int out_size, void* d_ws, size_t ws_size,
                              hipStream_t stream) {
    (void)in_sizes; (void)n_in; (void)out_size; (void)ws_size;
    const int*   x    = (const int*)  d_in[0];
    const float* pm   = (const float*)d_in[1];
    const float* emb  = (const float*)d_in[2];
    const float* ln1g = (const float*)d_in[3];
    const float* ln1b = (const float*)d_in[4];
    const float* wqr  = (const float*)d_in[5];
    const float* wkr  = (const float*)d_in[6];
    const float* wvr  = (const float*)d_in[7];
    const float* wor  = (const float*)d_in[8];
    const float* ln2g = (const float*)d_in[9];
    const float* ln2b = (const float*)d_in[10];
    const float* wqc  = (const float*)d_in[11];
    const float* wkc  = (const float*)d_in[12];
    const float* wvc  = (const float*)d_in[13];
    const float* woc  = (const float*)d_in[14];
    const float* ln3g = (const float*)d_in[15];
    const float* ln3b = (const float*)d_in[16];
    const float* fw1  = (const float*)d_in[17];
    const float* fb1  = (const float*)d_in[18];
    const float* fw2  = (const float*)d_in[19];
    const float* fb2  = (const float*)d_in[20];
    const float* pw1  = (const float*)d_in[21];
    const float* pb1  = (const float*)d_in[22];
    const float* pw2  = (const float*)d_in[23];
    const float* pb2  = (const float*)d_in[24];
    const float* uw   = (const float*)d_in[25];
    const float* ub   = (const float*)d_in[26];
    float* out = (float*)d_out;

    // workspace layout (f32): [h 36.2MB][z 36.2MB][big 144.7MB][y 141KB]
    float* h   = (float*)d_ws;
    float* z   = h + (size_t)MTOK * HH;
    float* big = z + (size_t)MTOK * HH;
    float* qb  = big;
    float* kb  = big + (size_t)MTOK * HH;
    float* vb  = big + 2 * (size_t)MTOK * HH;
    float* yb  = big + (size_t)MTOK * DFF;

    const dim3 gP (MTOK / 64, HH  / 64);
    const dim3 gF1(MTOK / 64, DFF / 64);

    k_embed<<<dim3(PP, CC), 256, 0, stream>>>(x, pm, emb, h);

    for (int i = 0; i < NBLK; ++i) {
        const size_t wo2 = (size_t)i * HH * HH;
        // ---- row attention (along C) ----
        k_ln<<<MTOK, 256, 0, stream>>>(h, z, ln1g + i * HH, ln1b + i * HH);
        k_gemm<false,false,false><<<gP, 256, 0, stream>>>(z, wqr + wo2, nullptr, qb, MTOK, HH, HH);
        k_gemm<false,false,false><<<gP, 256, 0, stream>>>(z, wkr + wo2, nullptr, kb, MTOK, HH, HH);
        k_gemm<false,false,false><<<gP, 256, 0, stream>>>(z, wvr + wo2, nullptr, vb, MTOK, HH, HH);
        k_attn<<<dim3(PP, NHEAD), 128, 0, stream>>>(qb, kb, vb, z, CC, CC, 1);
        k_gemm<false,false,true ><<<gP, 256, 0, stream>>>(z, wor + wo2, nullptr, h, MTOK, HH, HH);
        // ---- column attention (along P) ----
        k_ln<<<MTOK, 256, 0, stream>>>(h, z, ln2g + i * HH, ln2b + i * HH);
        k_gemm<false,false,false><<<gP, 256, 0, stream>>>(z, wqc + wo2, nullptr, qb, MTOK, HH, HH);
        k_gemm<false,false,false><<<gP, 256, 0, stream>>>(z, wkc + wo2, nullptr, kb, MTOK, HH, HH);
        k_gemm<false,false,false><<<gP, 256, 0, stream>>>(z, wvc + wo2, nullptr, vb, MTOK, HH, HH);
        k_attn<<<dim3(CC, NHEAD), 320, 0, stream>>>(qb, kb, vb, z, PP, 1, CC);
        k_gemm<false,false,true ><<<gP, 256, 0, stream>>>(z, woc + wo2, nullptr, h, MTOK, HH, HH);
        // ---- feed-forward ----
        k_ln<<<MTOK, 256, 0, stream>>>(h, z, ln3g + i * HH, ln3b + i * HH);
        k_gemm<true ,true ,false><<<gF1, 256, 0, stream>>>(z, fw1 + (size_t)i * HH * DFF, fb1 + i * DFF, big, MTOK, DFF, HH);
        k_gemm<true ,false,true ><<<gP , 256, 0, stream>>>(big, fw2 + (size_t)i * DFF * HH, fb2 + i * HH, h, MTOK, HH, DFF);
    }

    // ---- output head ----
    k_gemm<true,true,false><<<gF1, 256, 0, stream>>>(h, pw1, pb1, big, MTOK, DFF, HH);
    k_head1<<<MTOK, 256, 0, stream>>>(big, pw2, pb2, yb);
    k_head2<<<PP, 128, 0, stream>>>(yb, uw, ub, out);
}

// Round 3
// 1831.517 us; speedup vs baseline: 2.7910x; 2.5046x over previous
//
#include <hip/hip_runtime.h>
#include <math.h>

#define HH    256
#define NHEAD 8
#define HD    32
#define CC    128
#define RR    24
#define PP    276
#define NBLK  2
#define DFF   1024
#define MTOK  (PP*CC)   // 35328
#define CS    64        // attention K/V chunk rows staged in LDS

typedef float  f32x4  __attribute__((ext_vector_type(4)));
typedef short  bf16x8 __attribute__((ext_vector_type(8)));

__device__ __forceinline__ float gelu_f(float x) {
    return 0.5f * x * (1.0f + erff(x * 0.7071067811865476f));
}
__device__ __forceinline__ unsigned short f2b(float f) {
    unsigned u = __builtin_bit_cast(unsigned, f);
    unsigned r = (u + 0x7fffu + ((u >> 16) & 1u)) >> 16;
    return (unsigned short)r;
}
__device__ __forceinline__ float b2f(unsigned short b) {
    unsigned u = ((unsigned)b) << 16;
    return __builtin_bit_cast(float, u);
}

// ---------------------------------------------------------------------------
// h[p,c,:] = sum_r pm[p,r] * emb[x[r,c]]
// ---------------------------------------------------------------------------
__global__ __launch_bounds__(256) void k_embed(
    const int* __restrict__ x, const float* __restrict__ pm,
    const float* __restrict__ emb, float* __restrict__ h) {
    const int p = blockIdx.x, c = blockIdx.y, t = threadIdx.x;
    float acc = 0.f;
    for (int r = 0; r < RR; ++r) {
        float w = pm[p * RR + r];
        if (w != 0.f) {
            int tok = x[r * CC + c];
            acc += w * emb[(size_t)tok * HH + t];
        }
    }
    h[((size_t)p * CC + c) * HH + t] = acc;
}

// ---------------------------------------------------------------------------
// LayerNorm over H=256 per token, bf16 output. One block (256 thr) per row.
// ---------------------------------------------------------------------------
__global__ __launch_bounds__(256) void k_ln(
    const float* __restrict__ in, unsigned short* __restrict__ out,
    const float* __restrict__ g, const float* __restrict__ b) {
    const int row = blockIdx.x, t = threadIdx.x;
    const float xv = in[(size_t)row * HH + t];
    float s = xv, s2 = xv * xv;
    #pragma unroll
    for (int off = 32; off; off >>= 1) {
        s  += __shfl_down(s,  off);
        s2 += __shfl_down(s2, off);
    }
    __shared__ float sm[8];
    const int lane = t & 63, wid = t >> 6;
    if (lane == 0) { sm[wid] = s; sm[wid + 4] = s2; }
    __syncthreads();
    const float ssum  = sm[0] + sm[1] + sm[2] + sm[3];
    const float s2sum = sm[4] + sm[5] + sm[6] + sm[7];
    const float mean = ssum * (1.f / HH);
    const float var  = s2sum * (1.f / HH) - mean * mean;
    const float inv  = rsqrtf(var + 1e-5f);
    out[(size_t)row * HH + t] = f2b((xv - mean) * inv * g[t] + b[t]);
}

// ---------------------------------------------------------------------------
// Transpose + f32->bf16: src f32 [R][Cc] -> dst bf16 [Cc][R]; grid.z = matrix
// ---------------------------------------------------------------------------
__global__ __launch_bounds__(256) void k_cvtT(
    const float* __restrict__ src, unsigned short* __restrict__ dst,
    int R, int Cc) {
    __shared__ float tile[32][33];
    const size_t mo = (size_t)blockIdx.z * R * Cc;
    const int r0 = blockIdx.x * 32, c0 = blockIdx.y * 32;
    const int tx = threadIdx.x & 31, ty = threadIdx.x >> 5;  // 32 x 8
    #pragma unroll
    for (int i = 0; i < 4; ++i)
        tile[ty + 8 * i][tx] = src[mo + (size_t)(r0 + ty + 8 * i) * Cc + c0 + tx];
    __syncthreads();
    #pragma unroll
    for (int i = 0; i < 4; ++i)
        dst[mo + (size_t)(c0 + ty + 8 * i) * R + r0 + tx] = f2b(tile[tx][ty + 8 * i]);
}

// ---------------------------------------------------------------------------
// bf16 MFMA GEMM: C = [C +] act(A[M,K] @ Wt[N,K]^T [+ bias])
// 128x128 tile, BK=32, 256 threads = 4 waves, each wave 64x64 (4x4 frags of
// 16x16x32). LDS tiles XOR-swizzled (T2) -> conflict-free ds_read_b128.
// ---------------------------------------------------------------------------
#define BM 128
#define BN 128
#define BK 32
template<bool BIAS, bool GELU, bool RES, bool OF32, bool OBF16>
__global__ __launch_bounds__(256) void k_mgemm(
    const unsigned short* __restrict__ A,   // [M][K] bf16
    const unsigned short* __restrict__ Wt,  // [N][K] bf16 (pre-transposed)
    const float* __restrict__ bias,         // [N] f32
    float* __restrict__ C,                  // [M][N] f32
    unsigned short* __restrict__ Cb,        // [M][N] bf16 mirror
    int M, int N, int K) {
    __shared__ unsigned short Al[BM * BK];
    __shared__ unsigned short Bl[BN * BK];
    const int tid = threadIdx.x;
    const int wid = tid >> 6, lane = tid & 63;
    const int wr = wid >> 1, wc = wid & 1;        // wave -> 64x64 quadrant
    const int l16 = lane & 15, lh = lane >> 4;    // frag row/col, k-sub
    const int row0 = blockIdx.x * BM, col0 = blockIdx.y * BN;

    f32x4 acc[4][4];
    #pragma unroll
    for (int m = 0; m < 4; ++m)
        #pragma unroll
        for (int n = 0; n < 4; ++n) acc[m][n] = (f32x4){0.f, 0.f, 0.f, 0.f};

    for (int kt = 0; kt < K; kt += BK) {
        #pragma unroll
        for (int i = 0; i < 2; ++i) {           // stage A: 512 x 16B chunks
            int c = tid + i * 256;
            int r = c >> 2, part = c & 3;
            uint4 v = *(const uint4*)(A + (size_t)(row0 + r) * K + kt + part * 8);
            int bo = (r * 64 + part * 16) ^ ((r & 7) << 4);
            *(uint4*)((char*)Al + bo) = v;
        }
        #pragma unroll
        for (int i = 0; i < 2; ++i) {           // stage B (Wt rows = N)
            int c = tid + i * 256;
            int n = c >> 2, part = c & 3;
            uint4 v = *(const uint4*)(Wt + (size_t)(col0 + n) * K + kt + part * 8);
            int bo = (n * 64 + part * 16) ^ ((n & 7) << 4);
            *(uint4*)((char*)Bl + bo) = v;
        }
        __syncthreads();
        bf16x8 af[4], bf[4];
        #pragma unroll
        for (int m = 0; m < 4; ++m) {
            int r = wr * 64 + m * 16 + l16;
            int bo = (r * 64 + lh * 16) ^ ((r & 7) << 4);
            af[m] = *(const bf16x8*)((const char*)Al + bo);
        }
        #pragma unroll
        for (int n = 0; n < 4; ++n) {
            int nn = wc * 64 + n * 16 + l16;
            int bo = (nn * 64 + lh * 16) ^ ((nn & 7) << 4);
            bf[n] = *(const bf16x8*)((const char*)Bl + bo);
        }
        #pragma unroll
        for (int m = 0; m < 4; ++m)
            #pragma unroll
            for (int n = 0; n < 4; ++n)
                acc[m][n] = __builtin_amdgcn_mfma_f32_16x16x32_bf16(
                    af[m], bf[n], acc[m][n], 0, 0, 0);
        __syncthreads();
    }
    // epilogue: C/D layout col=lane&15, row=(lane>>4)*4+i  [m91-verified]
    #pragma unroll
    for (int m = 0; m < 4; ++m) {
        #pragma unroll
        for (int n = 0; n < 4; ++n) {
            const int colg = col0 + wc * 64 + n * 16 + l16;
            const float bv = BIAS ? bias[colg] : 0.f;
            #pragma unroll
            for (int i = 0; i < 4; ++i) {
                const int rowg = row0 + wr * 64 + m * 16 + lh * 4 + i;
                float v = acc[m][n][i] + bv;
                if (GELU) v = gelu_f(v);
                const size_t off = (size_t)rowg * N + colg;
                if (RES)   v += C[off];
                if (OF32)  C[off]  = v;
                if (OBF16) Cb[off] = f2b(v);
            }
        }
    }
}

// ---------------------------------------------------------------------------
// Attention (f32 in, bf16 out): one block per (sequence, head); one query per
// thread; K/V staged in LDS chunks; online softmax in 16-score sub-chunks.
// ---------------------------------------------------------------------------
__global__ __launch_bounds__(320) void k_attn(
    const float* __restrict__ q, const float* __restrict__ k,
    const float* __restrict__ v, unsigned short* __restrict__ o,
    int S, int base_mul, int stride) {
    const int seq = blockIdx.x, hd = blockIdx.y;
    const int base = seq * base_mul;
    const int t = threadIdx.x;
    const int nthr = blockDim.x;
    const float scale = 0.17677669529663687f;   // 1/sqrt(32)

    __shared__ float Ks[CS][HD];
    __shared__ float Vs[CS][HD];

    const int qi = t;
    const bool act = (qi < S);
    float qv[HD], accv[HD];
    float m = -1e30f, l = 0.f;
    if (act) {
        const float* qr = q + ((size_t)(base + qi * stride)) * HH + hd * HD;
        #pragma unroll
        for (int d = 0; d < HD; ++d) { qv[d] = qr[d] * scale; accv[d] = 0.f; }
    }

    for (int s0 = 0; s0 < S; s0 += CS) {
        for (int idx = t; idx < CS * (HD / 4); idx += nthr) {
            const int r = idx >> 3, d4 = (idx & 7) * 4;
            float4 kv, vv;
            if (s0 + r < S) {
                const size_t toff = ((size_t)(base + (s0 + r) * stride)) * HH + hd * HD + d4;
                kv = *(const float4*)&k[toff];
                vv = *(const float4*)&v[toff];
            } else {
                kv = make_float4(0.f, 0.f, 0.f, 0.f);
                vv = make_float4(0.f, 0.f, 0.f, 0.f);
            }
            *(float4*)&Ks[r][d4] = kv;
            *(float4*)&Vs[r][d4] = vv;
        }
        __syncthreads();
        if (act) {
            #pragma unroll
            for (int ss = 0; ss < CS; ss += 16) {
                float sc[16];
                #pragma unroll
                for (int j = 0; j < 16; ++j) {
                    float dot = 0.f;
                    #pragma unroll
                    for (int d = 0; d < HD; ++d) dot += qv[d] * Ks[ss + j][d];
                    sc[j] = (s0 + ss + j < S) ? dot : -1e30f;
                }
                float mx = m;
                #pragma unroll
                for (int j = 0; j < 16; ++j) mx = fmaxf(mx, sc[j]);
                const float corr = __expf(m - mx);
                m = mx;
                l *= corr;
                #pragma unroll
                for (int d = 0; d < HD; ++d) accv[d] *= corr;
                #pragma unroll
                for (int j = 0; j < 16; ++j) {
                    const float p = __expf(sc[j] - mx);
                    l += p;
                    #pragma unroll
                    for (int d = 0; d < HD; ++d) accv[d] += p * Vs[ss + j][d];
                }
            }
        }
        __syncthreads();
    }

    if (act) {
        const float inv = 1.f / l;
        unsigned short* orow = o + ((size_t)(base + qi * stride)) * HH + hd * HD;
        #pragma unroll
        for (int d = 0; d < HD; ++d) orow[d] = f2b(accv[d] * inv);
    }
}

// ---------------------------------------------------------------------------
__global__ __launch_bounds__(256) void k_head1(
    const unsigned short* __restrict__ g, const float* __restrict__ pw2,
    const float* __restrict__ pb2, float* __restrict__ y) {
    const int tok = blockIdx.x, t = threadIdx.x;
    const unsigned short* row = g + (size_t)tok * DFF;
    float s = 0.f;
    for (int f = t; f < DFF; f += 256) s += b2f(row[f]) * pw2[f];
    #pragma unroll
    for (int off = 32; off; off >>= 1) s += __shfl_down(s, off);
    __shared__ float sm[4];
    if ((t & 63) == 0) sm[t >> 6] = s;
    __syncthreads();
    if (t == 0) y[tok] = sm[0] + sm[1] + sm[2] + sm[3] + pb2[0];
}

__global__ __launch_bounds__(128) void k_head2(
    const float* __restrict__ y, const float* __restrict__ uw,
    const float* __restrict__ ub, float* __restrict__ out) {
    const int p = blockIdx.x, t = threadIdx.x;
    float s = y[(size_t)p * CC + t] * uw[t];
    #pragma unroll
    for (int off = 32; off; off >>= 1) s += __shfl_down(s, off);
    __shared__ float sm[2];
    if ((t & 63) == 0) sm[t >> 6] = s;
    __syncthreads();
    if (t == 0) out[p] = sm[0] + sm[1] + ub[0];
}

// ---------------------------------------------------------------------------
extern "C" void kernel_launch(void* const* d_in, const int* in_sizes, int n_in,
                              void* d_out, int out_size, void* d_ws, size_t ws_size,
                              hipStream_t stream) {
    (void)in_sizes; (void)n_in; (void)out_size; (void)ws_size;
    const int*   x    = (const int*)  d_in[0];
    const float* pm   = (const float*)d_in[1];
    const float* emb  = (const float*)d_in[2];
    const float* ln1g = (const float*)d_in[3];
    const float* ln1b = (const float*)d_in[4];
    const float* wqr  = (const float*)d_in[5];
    const float* wkr  = (const float*)d_in[6];
    const float* wvr  = (const float*)d_in[7];
    const float* wor  = (const float*)d_in[8];
    const float* ln2g = (const float*)d_in[9];
    const float* ln2b = (const float*)d_in[10];
    const float* wqc  = (const float*)d_in[11];
    const float* wkc  = (const float*)d_in[12];
    const float* wvc  = (const float*)d_in[13];
    const float* woc  = (const float*)d_in[14];
    const float* ln3g = (const float*)d_in[15];
    const float* ln3b = (const float*)d_in[16];
    const float* fw1  = (const float*)d_in[17];
    const float* fb1  = (const float*)d_in[18];
    const float* fw2  = (const float*)d_in[19];
    const float* fb2  = (const float*)d_in[20];
    const float* pw1  = (const float*)d_in[21];
    const float* pb1  = (const float*)d_in[22];
    const float* pw2  = (const float*)d_in[23];
    const float* pb2  = (const float*)d_in[24];
    const float* uw   = (const float*)d_in[25];
    const float* ub   = (const float*)d_in[26];
    float* out = (float*)d_out;

    // ---- workspace layout ----
    char* w = (char*)d_ws;
    float*          h   = (float*)w;                              // 36,175,872 B
    unsigned short* zb  = (unsigned short*)(w + 36175872);        // 18,087,936 B
    unsigned short* hb  = zb + (size_t)MTOK * HH;                 // 18,087,936 B
    unsigned short* wts = hb + (size_t)MTOK * HH;                 //  4,718,592 B
    float*          yb  = (float*)((char*)wts + 4718592);         //    141,312 B
    float*          scratch = (float*)((char*)yb + 141312);
    float* qb = scratch;
    float* kb = qb + (size_t)MTOK * HH;
    float* vb = kb + (size_t)MTOK * HH;
    unsigned short* bigb = (unsigned short*)scratch;              // aliases q/k/v (disjoint lifetime)

    unsigned short* wqr_t = wts;
    unsigned short* wkr_t = wqr_t + 2 * HH * HH;
    unsigned short* wvr_t = wkr_t + 2 * HH * HH;
    unsigned short* wor_t = wvr_t + 2 * HH * HH;
    unsigned short* wqc_t = wor_t + 2 * HH * HH;
    unsigned short* wkc_t = wqc_t + 2 * HH * HH;
    unsigned short* wvc_t = wkc_t + 2 * HH * HH;
    unsigned short* woc_t = wvc_t + 2 * HH * HH;
    unsigned short* fw1t  = woc_t + 2 * HH * HH;
    unsigned short* fw2t  = fw1t + 2 * HH * DFF;
    unsigned short* pw1t  = fw2t + 2 * HH * DFF;

    // ---- weight transpose+convert (f32 [K][N] -> bf16 [N][K]) ----
    k_cvtT<<<dim3(8, 8, 2),  256, 0, stream>>>(wqr, wqr_t, HH, HH);
    k_cvtT<<<dim3(8, 8, 2),  256, 0, stream>>>(wkr, wkr_t, HH, HH);
    k_cvtT<<<dim3(8, 8, 2),  256, 0, stream>>>(wvr, wvr_t, HH, HH);
    k_cvtT<<<dim3(8, 8, 2),  256, 0, stream>>>(wor, wor_t, HH, HH);
    k_cvtT<<<dim3(8, 8, 2),  256, 0, stream>>>(wqc, wqc_t, HH, HH);
    k_cvtT<<<dim3(8, 8, 2),  256, 0, stream>>>(wkc, wkc_t, HH, HH);
    k_cvtT<<<dim3(8, 8, 2),  256, 0, stream>>>(wvc, wvc_t, HH, HH);
    k_cvtT<<<dim3(8, 8, 2),  256, 0, stream>>>(woc, woc_t, HH, HH);
    k_cvtT<<<dim3(8, 32, 2), 256, 0, stream>>>(fw1, fw1t, HH, DFF);
    k_cvtT<<<dim3(32, 8, 2), 256, 0, stream>>>(fw2, fw2t, DFF, HH);
    k_cvtT<<<dim3(8, 32, 1), 256, 0, stream>>>(pw1, pw1t, HH, DFF);

    const dim3 gP (MTOK / BM, HH  / BN);   // (276, 2)
    const dim3 gF (MTOK / BM, DFF / BN);   // (276, 8)

    k_embed<<<dim3(PP, CC), 256, 0, stream>>>(x, pm, emb, h);

    for (int i = 0; i < NBLK; ++i) {
        const size_t po = (size_t)i * HH * HH;
        // ---- row attention (along C) ----
        k_ln<<<MTOK, 256, 0, stream>>>(h, zb, ln1g + i * HH, ln1b + i * HH);
        k_mgemm<false,false,false,true,false><<<gP, 256, 0, stream>>>(zb, wqr_t + po, nullptr, qb, nullptr, MTOK, HH, HH);
        k_mgemm<false,false,false,true,false><<<gP, 256, 0, stream>>>(zb, wkr_t + po, nullptr, kb, nullptr, MTOK, HH, HH);
        k_mgemm<false,false,false,true,false><<<gP, 256, 0, stream>>>(zb, wvr_t + po, nullptr, vb, nullptr, MTOK, HH, HH);
        k_attn<<<dim3(PP, NHEAD), 128, 0, stream>>>(qb, kb, vb, zb, CC, CC, 1);
        k_mgemm<false,false,true,true,false><<<gP, 256, 0, stream>>>(zb, wor_t + po, nullptr, h, nullptr, MTOK, HH, HH);
        // ---- column attention (along P) ----
        k_ln<<<MTOK, 256, 0, stream>>>(h, zb, ln2g + i * HH, ln2b + i * HH);
        k_mgemm<false,false,false,true,false><<<gP, 256, 0, stream>>>(zb, wqc_t + po, nullptr, qb, nullptr, MTOK, HH, HH);
        k_mgemm<false,false,false,true,false><<<gP, 256, 0, stream>>>(zb, wkc_t + po, nullptr, kb, nullptr, MTOK, HH, HH);
        k_mgemm<false,false,false,true,false><<<gP, 256, 0, stream>>>(zb, wvc_t + po, nullptr, vb, nullptr, MTOK, HH, HH);
        k_attn<<<dim3(CC, NHEAD), 320, 0, stream>>>(qb, kb, vb, zb, PP, 1, CC);
        k_mgemm<false,false,true,true,false><<<gP, 256, 0, stream>>>(zb, woc_t + po, nullptr, h, nullptr, MTOK, HH, HH);
        // ---- feed-forward ----
        k_ln<<<MTOK, 256, 0, stream>>>(h, zb, ln3g + i * HH, ln3b + i * HH);
        k_mgemm<true,true,false,false,true><<<gF, 256, 0, stream>>>(zb, fw1t + (size_t)i * HH * DFF, fb1 + i * DFF, nullptr, bigb, MTOK, DFF, HH);
        if (i == NBLK - 1)
            k_mgemm<true,false,true,true,true><<<gP, 256, 0, stream>>>(bigb, fw2t + (size_t)i * HH * DFF, fb2 + i * HH, h, hb, MTOK, HH, DFF);
        else
            k_mgemm<true,false,true,true,false><<<gP, 256, 0, stream>>>(bigb, fw2t + (size_t)i * HH * DFF, fb2 + i * HH, h, nullptr, MTOK, HH, DFF);
    }

    // ---- output head ----
    k_mgemm<true,true,false,false,true><<<gF, 256, 0, stream>>>(hb, pw1t, pb1, nullptr, bigb, MTOK, DFF, HH);
    k_head1<<<MTOK, 256, 0, stream>>>(bigb, pw2, pb2, yb);
    k_head2<<<PP, 128, 0, stream>>>(yb, uw, ub, out);
}

// Round 4
// 984.929 us; speedup vs baseline: 5.1899x; 1.8595x over previous
//
#include <hip/hip_runtime.h>
#include <math.h>

#define HH    256
#define NHEAD 8
#define HD    32
#define CC    128
#define RR    24
#define PP    276
#define NBLK  2
#define DFF   1024
#define MTOK  (PP*CC)   // 35328

typedef float          f32x4  __attribute__((ext_vector_type(4)));
typedef short          bf16x8 __attribute__((ext_vector_type(8)));
typedef unsigned short u16;

__device__ __forceinline__ float gelu_f(float x) {
    return 0.5f * x * (1.0f + erff(x * 0.7071067811865476f));
}
__device__ __forceinline__ u16 f2b(float f) {
    unsigned u = __builtin_bit_cast(unsigned, f);
    unsigned r = (u + 0x7fffu + ((u >> 16) & 1u)) >> 16;
    return (u16)r;
}
__device__ __forceinline__ float b2f(u16 b) {
    unsigned u = ((unsigned)b) << 16;
    return __builtin_bit_cast(float, u);
}
__device__ __forceinline__ unsigned cvt_pk_bf16(float lo, float hi) {
    unsigned r;
    asm("v_cvt_pk_bf16_f32 %0, %1, %2" : "=v"(r) : "v"(lo), "v"(hi));
    return r;
}

// ---------------------------------------------------------------------------
// h[p,c,:] = sum_r pm[p,r] * emb[x[r,c]]
// ---------------------------------------------------------------------------
__global__ __launch_bounds__(256) void k_embed(
    const int* __restrict__ x, const float* __restrict__ pm,
    const float* __restrict__ emb, float* __restrict__ h) {
    const int p = blockIdx.x, c = blockIdx.y, t = threadIdx.x;
    float acc = 0.f;
    for (int r = 0; r < RR; ++r) {
        float w = pm[p * RR + r];
        if (w != 0.f) {
            int tok = x[r * CC + c];
            acc += w * emb[(size_t)tok * HH + t];
        }
    }
    h[((size_t)p * CC + c) * HH + t] = acc;
}

// ---------------------------------------------------------------------------
// LayerNorm over H=256 per token, bf16 output. One block (256 thr) per row.
// ---------------------------------------------------------------------------
__global__ __launch_bounds__(256) void k_ln(
    const float* __restrict__ in, u16* __restrict__ out,
    const float* __restrict__ g, const float* __restrict__ b) {
    const int row = blockIdx.x, t = threadIdx.x;
    const float xv = in[(size_t)row * HH + t];
    float s = xv, s2 = xv * xv;
    #pragma unroll
    for (int off = 32; off; off >>= 1) {
        s  += __shfl_down(s,  off);
        s2 += __shfl_down(s2, off);
    }
    __shared__ float sm[8];
    const int lane = t & 63, wid = t >> 6;
    if (lane == 0) { sm[wid] = s; sm[wid + 4] = s2; }
    __syncthreads();
    const float ssum  = sm[0] + sm[1] + sm[2] + sm[3];
    const float s2sum = sm[4] + sm[5] + sm[6] + sm[7];
    const float mean = ssum * (1.f / HH);
    const float var  = s2sum * (1.f / HH) - mean * mean;
    const float inv  = rsqrtf(var + 1e-5f);
    out[(size_t)row * HH + t] = f2b((xv - mean) * inv * g[t] + b[t]);
}

// ---------------------------------------------------------------------------
// Transpose + f32->bf16: src f32 [R][Cc] -> dst bf16 [Cc][R]; grid.z = matrix
// ---------------------------------------------------------------------------
__global__ __launch_bounds__(256) void k_cvtT(
    const float* __restrict__ src, u16* __restrict__ dst, int R, int Cc) {
    __shared__ float tile[32][33];
    const size_t mo = (size_t)blockIdx.z * R * Cc;
    const int r0 = blockIdx.x * 32, c0 = blockIdx.y * 32;
    const int tx = threadIdx.x & 31, ty = threadIdx.x >> 5;  // 32 x 8
    #pragma unroll
    for (int i = 0; i < 4; ++i)
        tile[ty + 8 * i][tx] = src[mo + (size_t)(r0 + ty + 8 * i) * Cc + c0 + tx];
    __syncthreads();
    #pragma unroll
    for (int i = 0; i < 4; ++i)
        dst[mo + (size_t)(c0 + ty + 8 * i) * R + r0 + tx] = f2b(tile[tx][ty + 8 * i]);
}

// ---------------------------------------------------------------------------
// bf16 MFMA GEMM: C = [C +] act(omul*(A[M,K] @ Wt[N,K]^T) [+ bias])
// 128x128 tile, BK=32, 4 waves, each 64x64. XOR-swizzled LDS.
// ---------------------------------------------------------------------------
#define BM 128
#define BN 128
#define BK 32
template<bool BIAS, bool GELU, bool RES, bool OF32, bool OBF16>
__global__ __launch_bounds__(256) void k_mgemm(
    const u16* __restrict__ A,   // [M][K] bf16
    const u16* __restrict__ Wt,  // [N][K] bf16 (pre-transposed)
    const float* __restrict__ bias,
    float* __restrict__ C,       // [M][N] f32
    u16* __restrict__ Cb,        // [M][N] bf16 mirror
    int M, int N, int K, float omul) {
    __shared__ u16 Al[BM * BK];
    __shared__ u16 Bl[BN * BK];
    const int tid = threadIdx.x;
    const int wid = tid >> 6, lane = tid & 63;
    const int wr = wid >> 1, wc = wid & 1;
    const int l16 = lane & 15, lh = lane >> 4;
    const int row0 = blockIdx.x * BM, col0 = blockIdx.y * BN;

    f32x4 acc[4][4];
    #pragma unroll
    for (int m = 0; m < 4; ++m)
        #pragma unroll
        for (int n = 0; n < 4; ++n) acc[m][n] = (f32x4){0.f, 0.f, 0.f, 0.f};

    for (int kt = 0; kt < K; kt += BK) {
        #pragma unroll
        for (int i = 0; i < 2; ++i) {
            int c = tid + i * 256;
            int r = c >> 2, part = c & 3;
            uint4 v = *(const uint4*)(A + (size_t)(row0 + r) * K + kt + part * 8);
            int bo = (r * 64 + part * 16) ^ ((r & 7) << 4);
            *(uint4*)((char*)Al + bo) = v;
        }
        #pragma unroll
        for (int i = 0; i < 2; ++i) {
            int c = tid + i * 256;
            int n = c >> 2, part = c & 3;
            uint4 v = *(const uint4*)(Wt + (size_t)(col0 + n) * K + kt + part * 8);
            int bo = (n * 64 + part * 16) ^ ((n & 7) << 4);
            *(uint4*)((char*)Bl + bo) = v;
        }
        __syncthreads();
        bf16x8 af[4], bfr[4];
        #pragma unroll
        for (int m = 0; m < 4; ++m) {
            int r = wr * 64 + m * 16 + l16;
            int bo = (r * 64 + lh * 16) ^ ((r & 7) << 4);
            af[m] = *(const bf16x8*)((const char*)Al + bo);
        }
        #pragma unroll
        for (int n = 0; n < 4; ++n) {
            int nn = wc * 64 + n * 16 + l16;
            int bo = (nn * 64 + lh * 16) ^ ((nn & 7) << 4);
            bfr[n] = *(const bf16x8*)((const char*)Bl + bo);
        }
        #pragma unroll
        for (int m = 0; m < 4; ++m)
            #pragma unroll
            for (int n = 0; n < 4; ++n)
                acc[m][n] = __builtin_amdgcn_mfma_f32_16x16x32_bf16(
                    af[m], bfr[n], acc[m][n], 0, 0, 0);
        __syncthreads();
    }
    #pragma unroll
    for (int m = 0; m < 4; ++m) {
        #pragma unroll
        for (int n = 0; n < 4; ++n) {
            const int colg = col0 + wc * 64 + n * 16 + l16;
            const float bv = BIAS ? bias[colg] : 0.f;
            #pragma unroll
            for (int i = 0; i < 4; ++i) {
                const int rowg = row0 + wr * 64 + m * 16 + lh * 4 + i;
                float v = (acc[m][n][i] + bv) * omul;
                if (GELU) v = gelu_f(v);
                const size_t off = (size_t)rowg * N + colg;
                if (RES)   v += C[off];
                if (OF32)  C[off]  = v;
                if (OBF16) Cb[off] = f2b(v);
            }
        }
    }
}

// ---------------------------------------------------------------------------
// Fused MFMA flash attention (bf16 in/out, f32 softmax state).
// grid (nseq, NHEAD); token(idx) = blockIdx.x*base_mul + idx*stride.
// Swapped QK^T: S^T = mfma(K,Q) -> lane holds scores of query l16 (keys
// t*16+lh*4+i). O accumulated transposed: O^T = mfma(V^T, P^T).
// NQT query-16-tiles per wave. V^T staged in LDS [32][296].
// ---------------------------------------------------------------------------
template<int NQT>
__global__ __launch_bounds__(256) void k_fattn(
    const u16* __restrict__ qg, const u16* __restrict__ kg,
    const u16* __restrict__ vg, u16* __restrict__ og,
    int S, int base_mul, int stride) {
    const int head = blockIdx.y;
    const int base = blockIdx.x * base_mul;
    const int tid  = threadIdx.x;
    const int w = tid >> 6, lane = tid & 63;
    const int l16 = lane & 15, lh = lane >> 4;

    __shared__ u16 Vt[32 * 296];           // [d][key], stride 296 elems

    const int nkt = (S + 15) >> 4;         // 16-key tiles
    const int nch = (nkt + 1) >> 1;        // 32-key chunks
    const int KP  = nch * 32;

    // ---- stage V^T (zeros beyond S) ----
    for (int it = tid; it < KP * 4; it += blockDim.x) {
        const int key = it >> 2, d8 = (it & 3) * 8;
        uint4 t4 = make_uint4(0u, 0u, 0u, 0u);
        if (key < S)
            t4 = *(const uint4*)(vg + (size_t)(base + key * stride) * HH + head * HD + d8);
        Vt[(d8 + 0) * 296 + key] = (u16)(t4.x);
        Vt[(d8 + 1) * 296 + key] = (u16)(t4.x >> 16);
        Vt[(d8 + 2) * 296 + key] = (u16)(t4.y);
        Vt[(d8 + 3) * 296 + key] = (u16)(t4.y >> 16);
        Vt[(d8 + 4) * 296 + key] = (u16)(t4.z);
        Vt[(d8 + 5) * 296 + key] = (u16)(t4.z >> 16);
        Vt[(d8 + 6) * 296 + key] = (u16)(t4.w);
        Vt[(d8 + 7) * 296 + key] = (u16)(t4.w >> 16);
    }
    __syncthreads();

    // ---- per-wave state ----
    bf16x8 qf[NQT];
    #pragma unroll
    for (int j = 0; j < NQT; ++j) {
        int qi = (w * NQT + j) * 16 + l16;
        int qc = qi < S ? qi : S - 1;
        qf[j] = *(const bf16x8*)(qg + (size_t)(base + qc * stride) * HH + head * HD + lh * 8);
    }
    f32x4 acc[NQT][2];
    float mM[NQT], lL[NQT];
    #pragma unroll
    for (int j = 0; j < NQT; ++j) {
        acc[j][0] = (f32x4){0.f, 0.f, 0.f, 0.f};
        acc[j][1] = (f32x4){0.f, 0.f, 0.f, 0.f};
        mM[j] = -1e30f; lL[j] = 0.f;
    }

    auto ldK = [&](int kid) -> bf16x8 {
        int kc = kid < S ? kid : S - 1;
        return *(const bf16x8*)(kg + (size_t)(base + kc * stride) * HH + head * HD + lh * 8);
    };
    auto ldV = [&](int ch, int dm) -> bf16x8 {
        return *(const bf16x8*)(Vt + (dm * 16 + l16) * 296 + ch * 32 + lh * 8);
    };

    bf16x8 kc0 = ldK(l16), kc1 = ldK(16 + l16);
    bf16x8 vc0 = ldV(0, 0), vc1 = ldV(0, 1);
    const int g0 = 2 * (lh & 1);
    const int src0 = l16 + 16 * g0, src1 = src0 + 16;
    const bool hiT = (lh >> 1) & 1;
    const int lh4 = lh * 4;

    for (int ch = 0; ch < nch; ++ch) {
        bf16x8 kn0, kn1, vn0, vn1;
        if (ch + 1 < nch) {
            kn0 = ldK((ch + 1) * 32 + l16);
            kn1 = ldK((ch + 1) * 32 + 16 + l16);
            vn0 = ldV(ch + 1, 0);
            vn1 = ldV(ch + 1, 1);
        }
        const int kb = ch * 32;
        const bool fullv = (kb + 32 <= S);
        #pragma unroll
        for (int j = 0; j < NQT; ++j) {
            f32x4 s0 = __builtin_amdgcn_mfma_f32_16x16x32_bf16(
                kc0, qf[j], (f32x4){0.f, 0.f, 0.f, 0.f}, 0, 0, 0);
            f32x4 s1 = __builtin_amdgcn_mfma_f32_16x16x32_bf16(
                kc1, qf[j], (f32x4){0.f, 0.f, 0.f, 0.f}, 0, 0, 0);
            if (!fullv) {
                #pragma unroll
                for (int i = 0; i < 4; ++i) {
                    s0[i] = (kb + lh4 + i      < S) ? s0[i] : -1e30f;
                    s1[i] = (kb + 16 + lh4 + i < S) ? s1[i] : -1e30f;
                }
            }
            float mx = fmaxf(fmaxf(fmaxf(s0[0], s0[1]), fmaxf(s0[2], s0[3])),
                             fmaxf(fmaxf(s1[0], s1[1]), fmaxf(s1[2], s1[3])));
            mx = fmaxf(mx, __shfl_xor(mx, 16));
            mx = fmaxf(mx, __shfl_xor(mx, 32));
            const float mn = fmaxf(mM[j], mx);
            const float corr = __expf(mM[j] - mn);
            mM[j] = mn;
            float p0[4], p1[4], ls = 0.f;
            #pragma unroll
            for (int i = 0; i < 4; ++i) {
                p0[i] = __expf(s0[i] - mn); ls += p0[i];
                p1[i] = __expf(s1[i] - mn); ls += p1[i];
            }
            lL[j] = lL[j] * corr + ls;
            acc[j][0] *= corr;
            acc[j][1] *= corr;
            // pack P to bf16 words: w00/w01 = tile0 keys (g*4+{0,1},{2,3}),
            // w10/w11 = tile1. Exchange so lane lh gets keys lh*8..+7.
            const int w00 = (int)cvt_pk_bf16(p0[0], p0[1]);
            const int w01 = (int)cvt_pk_bf16(p0[2], p0[3]);
            const int w10 = (int)cvt_pk_bf16(p1[0], p1[1]);
            const int w11 = (int)cvt_pk_bf16(p1[2], p1[3]);
            uint4 W;
            { int a = __shfl(w00, src0), b = __shfl(w10, src0); W.x = (unsigned)(hiT ? b : a); }
            { int a = __shfl(w01, src0), b = __shfl(w11, src0); W.y = (unsigned)(hiT ? b : a); }
            { int a = __shfl(w00, src1), b = __shfl(w10, src1); W.z = (unsigned)(hiT ? b : a); }
            { int a = __shfl(w01, src1), b = __shfl(w11, src1); W.w = (unsigned)(hiT ? b : a); }
            const bf16x8 pw = __builtin_bit_cast(bf16x8, W);
            acc[j][0] = __builtin_amdgcn_mfma_f32_16x16x32_bf16(vc0, pw, acc[j][0], 0, 0, 0);
            acc[j][1] = __builtin_amdgcn_mfma_f32_16x16x32_bf16(vc1, pw, acc[j][1], 0, 0, 0);
        }
        kc0 = kn0; kc1 = kn1; vc0 = vn0; vc1 = vn1;
    }

    // ---- epilogue: reduce l across lh groups, write O (bf16) ----
    #pragma unroll
    for (int j = 0; j < NQT; ++j) {
        float lf = lL[j];
        lf += __shfl_xor(lf, 16);
        lf += __shfl_xor(lf, 32);
        const float inv = 1.f / lf;
        const int qi = (w * NQT + j) * 16 + l16;
        if (qi < S) {
            u16* dst = og + (size_t)(base + qi * stride) * HH + head * HD + lh4;
            #pragma unroll
            for (int dm = 0; dm < 2; ++dm) {
                uint2 o2;
                o2.x = cvt_pk_bf16(acc[j][dm][0] * inv, acc[j][dm][1] * inv);
                o2.y = cvt_pk_bf16(acc[j][dm][2] * inv, acc[j][dm][3] * inv);
                *(uint2*)(dst + dm * 16) = o2;
            }
        }
    }
}

// ---------------------------------------------------------------------------
__global__ __launch_bounds__(256) void k_head1(
    const u16* __restrict__ g, const float* __restrict__ pw2,
    const float* __restrict__ pb2, float* __restrict__ y) {
    const int tok = blockIdx.x, t = threadIdx.x;
    const u16* row = g + (size_t)tok * DFF;
    float s = 0.f;
    for (int f = t; f < DFF; f += 256) s += b2f(row[f]) * pw2[f];
    #pragma unroll
    for (int off = 32; off; off >>= 1) s += __shfl_down(s, off);
    __shared__ float sm[4];
    if ((t & 63) == 0) sm[t >> 6] = s;
    __syncthreads();
    if (t == 0) y[tok] = sm[0] + sm[1] + sm[2] + sm[3] + pb2[0];
}

__global__ __launch_bounds__(128) void k_head2(
    const float* __restrict__ y, const float* __restrict__ uw,
    const float* __restrict__ ub, float* __restrict__ out) {
    const int p = blockIdx.x, t = threadIdx.x;
    float s = y[(size_t)p * CC + t] * uw[t];
    #pragma unroll
    for (int off = 32; off; off >>= 1) s += __shfl_down(s, off);
    __shared__ float sm[2];
    if ((t & 63) == 0) sm[t >> 6] = s;
    __syncthreads();
    if (t == 0) out[p] = sm[0] + sm[1] + ub[0];
}

// ---------------------------------------------------------------------------
extern "C" void kernel_launch(void* const* d_in, const int* in_sizes, int n_in,
                              void* d_out, int out_size, void* d_ws, size_t ws_size,
                              hipStream_t stream) {
    (void)in_sizes; (void)n_in; (void)out_size; (void)ws_size;
    const int*   x    = (const int*)  d_in[0];
    const float* pm   = (const float*)d_in[1];
    const float* emb  = (const float*)d_in[2];
    const float* ln1g = (const float*)d_in[3];
    const float* ln1b = (const float*)d_in[4];
    const float* wqr  = (const float*)d_in[5];
    const float* wkr  = (const float*)d_in[6];
    const float* wvr  = (const float*)d_in[7];
    const float* wor  = (const float*)d_in[8];
    const float* ln2g = (const float*)d_in[9];
    const float* ln2b = (const float*)d_in[10];
    const float* wqc  = (const float*)d_in[11];
    const float* wkc  = (const float*)d_in[12];
    const float* wvc  = (const float*)d_in[13];
    const float* woc  = (const float*)d_in[14];
    const float* ln3g = (const float*)d_in[15];
    const float* ln3b = (const float*)d_in[16];
    const float* fw1  = (const float*)d_in[17];
    const float* fb1  = (const float*)d_in[18];
    const float* fw2  = (const float*)d_in[19];
    const float* fb2  = (const float*)d_in[20];
    const float* pw1  = (const float*)d_in[21];
    const float* pb1  = (const float*)d_in[22];
    const float* pw2  = (const float*)d_in[23];
    const float* pb2  = (const float*)d_in[24];
    const float* uw   = (const float*)d_in[25];
    const float* ub   = (const float*)d_in[26];
    float* out = (float*)d_out;

    // ---- workspace layout ----
    char* wsp = (char*)d_ws;
    float* h   = (float*)wsp;                              // 36,175,872 B
    u16*   zb  = (u16*)(wsp + 36175872);                   // 18,087,936 B
    u16*   hb  = zb + (size_t)MTOK * HH;                   // 18,087,936 B
    u16*   wts = hb + (size_t)MTOK * HH;                   //  4,718,592 B
    float* yb  = (float*)((char*)wts + 4718592);           //    141,312 B
    u16*   scratch = (u16*)((char*)yb + 141312);
    u16* qb = scratch;
    u16* kb = qb + (size_t)MTOK * HH;
    u16* vb = kb + (size_t)MTOK * HH;
    u16* bigb = scratch;                                   // FFN buffer, aliases q/k/v

    u16* wqr_t = wts;
    u16* wkr_t = wqr_t + 2 * HH * HH;
    u16* wvr_t = wkr_t + 2 * HH * HH;
    u16* wor_t = wvr_t + 2 * HH * HH;
    u16* wqc_t = wor_t + 2 * HH * HH;
    u16* wkc_t = wqc_t + 2 * HH * HH;
    u16* wvc_t = wkc_t + 2 * HH * HH;
    u16* woc_t = wvc_t + 2 * HH * HH;
    u16* fw1t  = woc_t + 2 * HH * HH;
    u16* fw2t  = fw1t + 2 * HH * DFF;
    u16* pw1t  = fw2t + 2 * HH * DFF;

    k_cvtT<<<dim3(8, 8, 2),  256, 0, stream>>>(wqr, wqr_t, HH, HH);
    k_cvtT<<<dim3(8, 8, 2),  256, 0, stream>>>(wkr, wkr_t, HH, HH);
    k_cvtT<<<dim3(8, 8, 2),  256, 0, stream>>>(wvr, wvr_t, HH, HH);
    k_cvtT<<<dim3(8, 8, 2),  256, 0, stream>>>(wor, wor_t, HH, HH);
    k_cvtT<<<dim3(8, 8, 2),  256, 0, stream>>>(wqc, wqc_t, HH, HH);
    k_cvtT<<<dim3(8, 8, 2),  256, 0, stream>>>(wkc, wkc_t, HH, HH);
    k_cvtT<<<dim3(8, 8, 2),  256, 0, stream>>>(wvc, wvc_t, HH, HH);
    k_cvtT<<<dim3(8, 8, 2),  256, 0, stream>>>(woc, woc_t, HH, HH);
    k_cvtT<<<dim3(8, 32, 2), 256, 0, stream>>>(fw1, fw1t, HH, DFF);
    k_cvtT<<<dim3(32, 8, 2), 256, 0, stream>>>(fw2, fw2t, DFF, HH);
    k_cvtT<<<dim3(8, 32, 1), 256, 0, stream>>>(pw1, pw1t, HH, DFF);

    const dim3 gP (MTOK / BM, HH  / BN);   // (276, 2)
    const dim3 gF (MTOK / BM, DFF / BN);   // (276, 8)
    const float qscale = 0.17677669529663687f;   // 1/sqrt(32)

    k_embed<<<dim3(PP, CC), 256, 0, stream>>>(x, pm, emb, h);

    for (int i = 0; i < NBLK; ++i) {
        const size_t po = (size_t)i * HH * HH;
        // ---- row attention (along C) ----
        k_ln<<<MTOK, 256, 0, stream>>>(h, zb, ln1g + i * HH, ln1b + i * HH);
        k_mgemm<false,false,false,false,true><<<gP, 256, 0, stream>>>(zb, wqr_t + po, nullptr, nullptr, qb, MTOK, HH, HH, qscale);
        k_mgemm<false,false,false,false,true><<<gP, 256, 0, stream>>>(zb, wkr_t + po, nullptr, nullptr, kb, MTOK, HH, HH, 1.f);
        k_mgemm<false,false,false,false,true><<<gP, 256, 0, stream>>>(zb, wvr_t + po, nullptr, nullptr, vb, MTOK, HH, HH, 1.f);
        k_fattn<2><<<dim3(PP, NHEAD), 256, 0, stream>>>(qb, kb, vb, zb, CC, CC, 1);
        k_mgemm<false,false,true,true,false><<<gP, 256, 0, stream>>>(zb, wor_t + po, nullptr, h, nullptr, MTOK, HH, HH, 1.f);
        // ---- column attention (along P) ----
        k_ln<<<MTOK, 256, 0, stream>>>(h, zb, ln2g + i * HH, ln2b + i * HH);
        k_mgemm<false,false,false,false,true><<<gP, 256, 0, stream>>>(zb, wqc_t + po, nullptr, nullptr, qb, MTOK, HH, HH, qscale);
        k_mgemm<false,false,false,false,true><<<gP, 256, 0, stream>>>(zb, wkc_t + po, nullptr, nullptr, kb, MTOK, HH, HH, 1.f);
        k_mgemm<false,false,false,false,true><<<gP, 256, 0, stream>>>(zb, wvc_t + po, nullptr, nullptr, vb, MTOK, HH, HH, 1.f);
        k_fattn<6><<<dim3(CC, NHEAD), 192, 0, stream>>>(qb, kb, vb, zb, PP, 1, CC);
        k_mgemm<false,false,true,true,false><<<gP, 256, 0, stream>>>(zb, woc_t + po, nullptr, h, nullptr, MTOK, HH, HH, 1.f);
        // ---- feed-forward ----
        k_ln<<<MTOK, 256, 0, stream>>>(h, zb, ln3g + i * HH, ln3b + i * HH);
        k_mgemm<true,true,false,false,true><<<gF, 256, 0, stream>>>(zb, fw1t + (size_t)i * HH * DFF, fb1 + i * DFF, nullptr, bigb, MTOK, DFF, HH, 1.f);
        if (i == NBLK - 1)
            k_mgemm<true,false,true,true,true><<<gP, 256, 0, stream>>>(bigb, fw2t + (size_t)i * HH * DFF, fb2 + i * HH, h, hb, MTOK, HH, DFF, 1.f);
        else
            k_mgemm<true,false,true,true,false><<<gP, 256, 0, stream>>>(bigb, fw2t + (size_t)i * HH * DFF, fb2 + i * HH, h, nullptr, MTOK, HH, DFF, 1.f);
    }

    // ---- output head ----
    k_mgemm<true,true,false,false,true><<<gF, 256, 0, stream>>>(hb, pw1t, pb1, nullptr, bigb, MTOK, DFF, HH, 1.f);
    k_head1<<<MTOK, 256, 0, stream>>>(bigb, pw2, pb2, yb);
    k_head2<<<PP, 128, 0, stream>>>(yb, uw, ub, out);
}

// Round 5
// 864.144 us; speedup vs baseline: 5.9154x; 1.1398x over previous
//
#include <hip/hip_runtime.h>
#include <math.h>

#define HH    256
#define NHEAD 8
#define HD    32
#define CC    128
#define RR    24
#define PP    276
#define NBLK  2
#define DFF   1024
#define MTOK  (PP*CC)   // 35328

typedef float          f32x4  __attribute__((ext_vector_type(4)));
typedef short          bf16x8 __attribute__((ext_vector_type(8)));
typedef unsigned short u16;

__device__ __forceinline__ float gelu_f(float x) {
    return 0.5f * x * (1.0f + erff(x * 0.7071067811865476f));
}
__device__ __forceinline__ u16 f2b(float f) {
    unsigned u = __builtin_bit_cast(unsigned, f);
    unsigned r = (u + 0x7fffu + ((u >> 16) & 1u)) >> 16;
    return (u16)r;
}
__device__ __forceinline__ float b2f(u16 b) {
    unsigned u = ((unsigned)b) << 16;
    return __builtin_bit_cast(float, u);
}
__device__ __forceinline__ unsigned cvt_pk_bf16(float lo, float hi) {
    unsigned r;
    asm("v_cvt_pk_bf16_f32 %0, %1, %2" : "=v"(r) : "v"(lo), "v"(hi));
    return r;
}
// async global->LDS, 16B per lane; LDS dest = wave-uniform base + lane*16
__device__ __forceinline__ void gload16(const void* g, void* l) {
    __builtin_amdgcn_global_load_lds(
        (const __attribute__((address_space(1))) unsigned int*)g,
        (__attribute__((address_space(3))) unsigned int*)l, 16, 0, 0);
}

// ---------------------------------------------------------------------------
// h[p,c,:] = sum_r pm[p,r] * emb[x[r,c]]
// ---------------------------------------------------------------------------
__global__ __launch_bounds__(256) void k_embed(
    const int* __restrict__ x, const float* __restrict__ pm,
    const float* __restrict__ emb, float* __restrict__ h) {
    const int p = blockIdx.x, c = blockIdx.y, t = threadIdx.x;
    float acc = 0.f;
    for (int r = 0; r < RR; ++r) {
        float w = pm[p * RR + r];
        if (w != 0.f) {
            int tok = x[r * CC + c];
            acc += w * emb[(size_t)tok * HH + t];
        }
    }
    h[((size_t)p * CC + c) * HH + t] = acc;
}

// ---------------------------------------------------------------------------
// LayerNorm over H=256 per token, bf16 output. One block (256 thr) per row.
// ---------------------------------------------------------------------------
__global__ __launch_bounds__(256) void k_ln(
    const float* __restrict__ in, u16* __restrict__ out,
    const float* __restrict__ g, const float* __restrict__ b) {
    const int row = blockIdx.x, t = threadIdx.x;
    const float xv = in[(size_t)row * HH + t];
    float s = xv, s2 = xv * xv;
    #pragma unroll
    for (int off = 32; off; off >>= 1) {
        s  += __shfl_down(s,  off);
        s2 += __shfl_down(s2, off);
    }
    __shared__ float sm[8];
    const int lane = t & 63, wid = t >> 6;
    if (lane == 0) { sm[wid] = s; sm[wid + 4] = s2; }
    __syncthreads();
    const float ssum  = sm[0] + sm[1] + sm[2] + sm[3];
    const float s2sum = sm[4] + sm[5] + sm[6] + sm[7];
    const float mean = ssum * (1.f / HH);
    const float var  = s2sum * (1.f / HH) - mean * mean;
    const float inv  = rsqrtf(var + 1e-5f);
    out[(size_t)row * HH + t] = f2b((xv - mean) * inv * g[t] + b[t]);
}

// ---------------------------------------------------------------------------
// Transpose + f32->bf16 (+scale): src f32 [R][Cc] -> dst bf16 [Cc][R]
// blockIdx.z selects matrix: src += z*R*Cc, dst += z*dstStride
// ---------------------------------------------------------------------------
__global__ __launch_bounds__(256) void k_cvtT(
    const float* __restrict__ src, u16* __restrict__ dst,
    int R, int Cc, int dstStride, float mul) {
    __shared__ float tile[32][33];
    const size_t so = (size_t)blockIdx.z * R * Cc;
    const size_t dOff = (size_t)blockIdx.z * dstStride;
    const int r0 = blockIdx.x * 32, c0 = blockIdx.y * 32;
    const int tx = threadIdx.x & 31, ty = threadIdx.x >> 5;  // 32 x 8
    #pragma unroll
    for (int i = 0; i < 4; ++i)
        tile[ty + 8 * i][tx] = src[so + (size_t)(r0 + ty + 8 * i) * Cc + c0 + tx];
    __syncthreads();
    #pragma unroll
    for (int i = 0; i < 4; ++i)
        dst[dOff + (size_t)(c0 + ty + 8 * i) * R + r0 + tx] = f2b(mul * tile[tx][ty + 8 * i]);
}

// ---------------------------------------------------------------------------
// bf16 MFMA GEMM: C = [C +] act(A[M,K] @ Wt[N,K]^T [+ bias])
// 128x128 tile, BK=32, 4 waves. Double-buffered global_load_lds(16B) staging
// into linear LDS with inverse-swizzled SOURCE lanes (rule 21); involutory
// within-row chunk swizzle p^=(r>>1)&3 -> 2-way (free) ds_read_b128 banking.
// 1-D grid, XCD-chunked swizzle, col-tile fastest (requires nwg % 8 == 0).
// ---------------------------------------------------------------------------
#define BM 128
#define BN 128
#define BK 32
template<bool BIAS, bool GELU, bool RES, bool OF32, bool OBF16>
__global__ __launch_bounds__(256) void k_mgemm(
    const u16* __restrict__ A,   // [M][K] bf16
    const u16* __restrict__ Wt,  // [N][K] bf16 (pre-transposed)
    const float* __restrict__ bias,
    float* __restrict__ C,       // [M][N] f32
    u16* __restrict__ Cb,        // [M][N] bf16 mirror
    int M, int N, int K) {
    __shared__ u16 Al[2][BM * BK];
    __shared__ u16 Bl[2][BN * BK];
    const int tid = threadIdx.x;
    const int wid = tid >> 6, lane = tid & 63;
    const int wr = wid >> 1, wc = wid & 1;
    const int l16 = lane & 15, lh = lane >> 4;

    // XCD-chunked block swizzle: each XCD gets a contiguous chunk of tiles,
    // col-tile fastest within chunk -> A-panel reuse lands in that XCD's L2.
    const int nwg = gridDim.x;
    const int ntx = N >> 7;                    // N / BN
    const int swz = (blockIdx.x & 7) * (nwg >> 3) + (blockIdx.x >> 3);
    const int row0 = (swz / ntx) * BM, col0 = (swz % ntx) * BN;

    // stage mapping: dest chunk d -> logical (row r, k-part p)
    int rS[2], pS[2];
    #pragma unroll
    for (int i = 0; i < 2; ++i) {
        const int d = tid + i * 256;
        rS[i] = d >> 2;
        pS[i] = (d & 3) ^ ((rS[i] >> 1) & 3);
    }
    const int nt = K / BK;

    auto stage = [&](int buf, int kt) {
        #pragma unroll
        for (int i = 0; i < 2; ++i) {
            gload16(A  + (size_t)(row0 + rS[i]) * K + kt + pS[i] * 8,
                    (char*)&Al[buf][0] + (wid * 64 + i * 256) * 16);
            gload16(Wt + (size_t)(col0 + rS[i]) * K + kt + pS[i] * 8,
                    (char*)&Bl[buf][0] + (wid * 64 + i * 256) * 16);
        }
    };

    f32x4 acc[4][4];
    #pragma unroll
    for (int m = 0; m < 4; ++m)
        #pragma unroll
        for (int n = 0; n < 4; ++n) acc[m][n] = (f32x4){0.f, 0.f, 0.f, 0.f};

    stage(0, 0);
    __syncthreads();
    for (int t = 0; t < nt; ++t) {
        const int cur = t & 1;
        if (t + 1 < nt) stage(cur ^ 1, (t + 1) * BK);
        bf16x8 af[4], bfr[4];
        #pragma unroll
        for (int m = 0; m < 4; ++m) {
            const int r = wr * 64 + m * 16 + l16;
            af[m] = *(const bf16x8*)((const char*)&Al[cur][0]
                     + r * 64 + ((lh ^ ((r >> 1) & 3)) << 4));
        }
        #pragma unroll
        for (int n = 0; n < 4; ++n) {
            const int nn = wc * 64 + n * 16 + l16;
            bfr[n] = *(const bf16x8*)((const char*)&Bl[cur][0]
                     + nn * 64 + ((lh ^ ((nn >> 1) & 3)) << 4));
        }
        #pragma unroll
        for (int m = 0; m < 4; ++m)
            #pragma unroll
            for (int n = 0; n < 4; ++n)
                acc[m][n] = __builtin_amdgcn_mfma_f32_16x16x32_bf16(
                    af[m], bfr[n], acc[m][n], 0, 0, 0);
        __syncthreads();
    }
    // epilogue: C/D layout col=lane&15, row=(lane>>4)*4+i
    #pragma unroll
    for (int m = 0; m < 4; ++m) {
        #pragma unroll
        for (int n = 0; n < 4; ++n) {
            const int colg = col0 + wc * 64 + n * 16 + l16;
            const float bv = BIAS ? bias[colg] : 0.f;
            #pragma unroll
            for (int i = 0; i < 4; ++i) {
                const int rowg = row0 + wr * 64 + m * 16 + lh * 4 + i;
                float v = acc[m][n][i] + bv;
                if (GELU) v = gelu_f(v);
                const size_t off = (size_t)rowg * N + colg;
                if (RES)   v += C[off];
                if (OF32)  C[off]  = v;
                if (OBF16) Cb[off] = f2b(v);
            }
        }
    }
}

// ---------------------------------------------------------------------------
// Fused MFMA flash attention (bf16 in/out, f32 softmax state).
// Inputs have row stride rowH (shared QKV buffer); output row stride HH.
// Swapped QK^T: S^T = mfma(K,Q) -> lane holds scores of query l16.
// O accumulated transposed: O^T = mfma(V^T, P^T). V^T staged in LDS [32][296].
// ---------------------------------------------------------------------------
template<int NQT>
__global__ __launch_bounds__(256) void k_fattn(
    const u16* __restrict__ qg, const u16* __restrict__ kg,
    const u16* __restrict__ vg, u16* __restrict__ og,
    int S, int base_mul, int stride, int rowH) {
    const int head = blockIdx.y;
    const int base = blockIdx.x * base_mul;
    const int tid  = threadIdx.x;
    const int w = tid >> 6, lane = tid & 63;
    const int l16 = lane & 15, lh = lane >> 4;

    __shared__ u16 Vt[32 * 296];           // [d][key], stride 296 elems

    const int nkt = (S + 15) >> 4;
    const int nch = (nkt + 1) >> 1;
    const int KP  = nch * 32;

    for (int it = tid; it < KP * 4; it += blockDim.x) {
        const int key = it >> 2, d8 = (it & 3) * 8;
        uint4 t4 = make_uint4(0u, 0u, 0u, 0u);
        if (key < S)
            t4 = *(const uint4*)(vg + (size_t)(base + key * stride) * rowH + head * HD + d8);
        Vt[(d8 + 0) * 296 + key] = (u16)(t4.x);
        Vt[(d8 + 1) * 296 + key] = (u16)(t4.x >> 16);
        Vt[(d8 + 2) * 296 + key] = (u16)(t4.y);
        Vt[(d8 + 3) * 296 + key] = (u16)(t4.y >> 16);
        Vt[(d8 + 4) * 296 + key] = (u16)(t4.z);
        Vt[(d8 + 5) * 296 + key] = (u16)(t4.z >> 16);
        Vt[(d8 + 6) * 296 + key] = (u16)(t4.w);
        Vt[(d8 + 7) * 296 + key] = (u16)(t4.w >> 16);
    }
    __syncthreads();

    bf16x8 qf[NQT];
    #pragma unroll
    for (int j = 0; j < NQT; ++j) {
        int qi = (w * NQT + j) * 16 + l16;
        int qc = qi < S ? qi : S - 1;
        qf[j] = *(const bf16x8*)(qg + (size_t)(base + qc * stride) * rowH + head * HD + lh * 8);
    }
    f32x4 acc[NQT][2];
    float mM[NQT], lL[NQT];
    #pragma unroll
    for (int j = 0; j < NQT; ++j) {
        acc[j][0] = (f32x4){0.f, 0.f, 0.f, 0.f};
        acc[j][1] = (f32x4){0.f, 0.f, 0.f, 0.f};
        mM[j] = -1e30f; lL[j] = 0.f;
    }

    auto ldK = [&](int kid) -> bf16x8 {
        int kc = kid < S ? kid : S - 1;
        return *(const bf16x8*)(kg + (size_t)(base + kc * stride) * rowH + head * HD + lh * 8);
    };
    auto ldV = [&](int ch, int dm) -> bf16x8 {
        return *(const bf16x8*)(Vt + (dm * 16 + l16) * 296 + ch * 32 + lh * 8);
    };

    bf16x8 kc0 = ldK(l16), kc1 = ldK(16 + l16);
    bf16x8 vc0 = ldV(0, 0), vc1 = ldV(0, 1);
    const int g0 = 2 * (lh & 1);
    const int src0 = l16 + 16 * g0, src1 = src0 + 16;
    const bool hiT = (lh >> 1) & 1;
    const int lh4 = lh * 4;

    for (int ch = 0; ch < nch; ++ch) {
        bf16x8 kn0, kn1, vn0, vn1;
        if (ch + 1 < nch) {
            kn0 = ldK((ch + 1) * 32 + l16);
            kn1 = ldK((ch + 1) * 32 + 16 + l16);
            vn0 = ldV(ch + 1, 0);
            vn1 = ldV(ch + 1, 1);
        }
        const int kb = ch * 32;
        const bool fullv = (kb + 32 <= S);
        #pragma unroll
        for (int j = 0; j < NQT; ++j) {
            f32x4 s0 = __builtin_amdgcn_mfma_f32_16x16x32_bf16(
                kc0, qf[j], (f32x4){0.f, 0.f, 0.f, 0.f}, 0, 0, 0);
            f32x4 s1 = __builtin_amdgcn_mfma_f32_16x16x32_bf16(
                kc1, qf[j], (f32x4){0.f, 0.f, 0.f, 0.f}, 0, 0, 0);
            if (!fullv) {
                #pragma unroll
                for (int i = 0; i < 4; ++i) {
                    s0[i] = (kb + lh4 + i      < S) ? s0[i] : -1e30f;
                    s1[i] = (kb + 16 + lh4 + i < S) ? s1[i] : -1e30f;
                }
            }
            float mx = fmaxf(fmaxf(fmaxf(s0[0], s0[1]), fmaxf(s0[2], s0[3])),
                             fmaxf(fmaxf(s1[0], s1[1]), fmaxf(s1[2], s1[3])));
            mx = fmaxf(mx, __shfl_xor(mx, 16));
            mx = fmaxf(mx, __shfl_xor(mx, 32));
            const float mn = fmaxf(mM[j], mx);
            const float corr = __expf(mM[j] - mn);
            mM[j] = mn;
            float p0[4], p1[4], ls = 0.f;
            #pragma unroll
            for (int i = 0; i < 4; ++i) {
                p0[i] = __expf(s0[i] - mn); ls += p0[i];
                p1[i] = __expf(s1[i] - mn); ls += p1[i];
            }
            lL[j] = lL[j] * corr + ls;
            acc[j][0] *= corr;
            acc[j][1] *= corr;
            const int w00 = (int)cvt_pk_bf16(p0[0], p0[1]);
            const int w01 = (int)cvt_pk_bf16(p0[2], p0[3]);
            const int w10 = (int)cvt_pk_bf16(p1[0], p1[1]);
            const int w11 = (int)cvt_pk_bf16(p1[2], p1[3]);
            uint4 W;
            { int a = __shfl(w00, src0), b = __shfl(w10, src0); W.x = (unsigned)(hiT ? b : a); }
            { int a = __shfl(w01, src0), b = __shfl(w11, src0); W.y = (unsigned)(hiT ? b : a); }
            { int a = __shfl(w00, src1), b = __shfl(w10, src1); W.z = (unsigned)(hiT ? b : a); }
            { int a = __shfl(w01, src1), b = __shfl(w11, src1); W.w = (unsigned)(hiT ? b : a); }
            const bf16x8 pw = __builtin_bit_cast(bf16x8, W);
            acc[j][0] = __builtin_amdgcn_mfma_f32_16x16x32_bf16(vc0, pw, acc[j][0], 0, 0, 0);
            acc[j][1] = __builtin_amdgcn_mfma_f32_16x16x32_bf16(vc1, pw, acc[j][1], 0, 0, 0);
        }
        kc0 = kn0; kc1 = kn1; vc0 = vn0; vc1 = vn1;
    }

    #pragma unroll
    for (int j = 0; j < NQT; ++j) {
        float lf = lL[j];
        lf += __shfl_xor(lf, 16);
        lf += __shfl_xor(lf, 32);
        const float inv = 1.f / lf;
        const int qi = (w * NQT + j) * 16 + l16;
        if (qi < S) {
            u16* dst = og + (size_t)(base + qi * stride) * HH + head * HD + lh4;
            #pragma unroll
            for (int dm = 0; dm < 2; ++dm) {
                uint2 o2;
                o2.x = cvt_pk_bf16(acc[j][dm][0] * inv, acc[j][dm][1] * inv);
                o2.y = cvt_pk_bf16(acc[j][dm][2] * inv, acc[j][dm][3] * inv);
                *(uint2*)(dst + dm * 16) = o2;
            }
        }
    }
}

// ---------------------------------------------------------------------------
__global__ __launch_bounds__(256) void k_head1(
    const u16* __restrict__ g, const float* __restrict__ pw2,
    const float* __restrict__ pb2, float* __restrict__ y) {
    const int tok = blockIdx.x, t = threadIdx.x;
    const u16* row = g + (size_t)tok * DFF;
    float s = 0.f;
    for (int f = t; f < DFF; f += 256) s += b2f(row[f]) * pw2[f];
    #pragma unroll
    for (int off = 32; off; off >>= 1) s += __shfl_down(s, off);
    __shared__ float sm[4];
    if ((t & 63) == 0) sm[t >> 6] = s;
    __syncthreads();
    if (t == 0) y[tok] = sm[0] + sm[1] + sm[2] + sm[3] + pb2[0];
}

__global__ __launch_bounds__(128) void k_head2(
    const float* __restrict__ y, const float* __restrict__ uw,
    const float* __restrict__ ub, float* __restrict__ out) {
    const int p = blockIdx.x, t = threadIdx.x;
    float s = y[(size_t)p * CC + t] * uw[t];
    #pragma unroll
    for (int off = 32; off; off >>= 1) s += __shfl_down(s, off);
    __shared__ float sm[2];
    if ((t & 63) == 0) sm[t >> 6] = s;
    __syncthreads();
    if (t == 0) out[p] = sm[0] + sm[1] + ub[0];
}

// ---------------------------------------------------------------------------
extern "C" void kernel_launch(void* const* d_in, const int* in_sizes, int n_in,
                              void* d_out, int out_size, void* d_ws, size_t ws_size,
                              hipStream_t stream) {
    (void)in_sizes; (void)n_in; (void)out_size; (void)ws_size;
    const int*   x    = (const int*)  d_in[0];
    const float* pm   = (const float*)d_in[1];
    const float* emb  = (const float*)d_in[2];
    const float* ln1g = (const float*)d_in[3];
    const float* ln1b = (const float*)d_in[4];
    const float* wqr  = (const float*)d_in[5];
    const float* wkr  = (const float*)d_in[6];
    const float* wvr  = (const float*)d_in[7];
    const float* wor  = (const float*)d_in[8];
    const float* ln2g = (const float*)d_in[9];
    const float* ln2b = (const float*)d_in[10];
    const float* wqc  = (const float*)d_in[11];
    const float* wkc  = (const float*)d_in[12];
    const float* wvc  = (const float*)d_in[13];
    const float* woc  = (const float*)d_in[14];
    const float* ln3g = (const float*)d_in[15];
    const float* ln3b = (const float*)d_in[16];
    const float* fw1  = (const float*)d_in[17];
    const float* fb1  = (const float*)d_in[18];
    const float* fw2  = (const float*)d_in[19];
    const float* fb2  = (const float*)d_in[20];
    const float* pw1  = (const float*)d_in[21];
    const float* pb1  = (const float*)d_in[22];
    const float* pw2  = (const float*)d_in[23];
    const float* pb2  = (const float*)d_in[24];
    const float* uw   = (const float*)d_in[25];
    const float* ub   = (const float*)d_in[26];
    float* out = (float*)d_out;

    // ---- workspace layout ----
    char* wsp = (char*)d_ws;
    float* h   = (float*)wsp;                              // 36,175,872 B
    u16*   zb  = (u16*)(wsp + 36175872);                   // 18,087,936 B
    u16*   hb  = zb + (size_t)MTOK * HH;                   // 18,087,936 B
    u16*   wts = hb + (size_t)MTOK * HH;                   //  4,718,592 B
    float* yb  = (float*)((char*)wts + 4718592);           //    141,312 B
    u16*   scratch = (u16*)((char*)yb + 141312);
    u16* qkvb = scratch;                                   // [MTOK][768] bf16 (54 MB)
    u16* bigb = scratch;                                   // [MTOK][1024] bf16 (72 MB), aliased

    // weight buffers (bf16, transposed [N][K])
    u16* wqkvr_t = wts;                                    // 2 x [768][256]
    u16* wqkvc_t = wqkvr_t + 2 * 768 * HH;                 // 2 x [768][256]
    u16* wor_t   = wqkvc_t + 2 * 768 * HH;                 // 2 x [256][256]
    u16* woc_t   = wor_t + 2 * HH * HH;
    u16* fw1t    = woc_t + 2 * HH * HH;                    // 2 x [1024][256]
    u16* fw2t    = fw1t + 2 * HH * DFF;                    // 2 x [256][1024]
    u16* pw1t    = fw2t + 2 * HH * DFF;                    // [1024][256]

    const float qscale = 0.17677669529663687f;   // 1/sqrt(32), folded into wq
    const int QKVS = 768 * HH;                   // per-layer qkv weight stride

    k_cvtT<<<dim3(8, 8, 2),  256, 0, stream>>>(wqr, wqkvr_t,            HH, HH, QKVS, qscale);
    k_cvtT<<<dim3(8, 8, 2),  256, 0, stream>>>(wkr, wqkvr_t + 256 * HH, HH, HH, QKVS, 1.f);
    k_cvtT<<<dim3(8, 8, 2),  256, 0, stream>>>(wvr, wqkvr_t + 512 * HH, HH, HH, QKVS, 1.f);
    k_cvtT<<<dim3(8, 8, 2),  256, 0, stream>>>(wqc, wqkvc_t,            HH, HH, QKVS, qscale);
    k_cvtT<<<dim3(8, 8, 2),  256, 0, stream>>>(wkc, wqkvc_t + 256 * HH, HH, HH, QKVS, 1.f);
    k_cvtT<<<dim3(8, 8, 2),  256, 0, stream>>>(wvc, wqkvc_t + 512 * HH, HH, HH, QKVS, 1.f);
    k_cvtT<<<dim3(8, 8, 2),  256, 0, stream>>>(wor, wor_t, HH, HH, HH * HH, 1.f);
    k_cvtT<<<dim3(8, 8, 2),  256, 0, stream>>>(woc, woc_t, HH, HH, HH * HH, 1.f);
    k_cvtT<<<dim3(8, 32, 2), 256, 0, stream>>>(fw1, fw1t, HH, DFF, HH * DFF, 1.f);
    k_cvtT<<<dim3(32, 8, 2), 256, 0, stream>>>(fw2, fw2t, DFF, HH, HH * DFF, 1.f);
    k_cvtT<<<dim3(8, 32, 1), 256, 0, stream>>>(pw1, pw1t, HH, DFF, 0, 1.f);

    // 1-D grids (all divisible by 8 for the XCD swizzle)
    const int gQKV = (MTOK / BM) * (768 / BN);   // 1656
    const int gO   = (MTOK / BM) * (HH  / BN);   // 552
    const int gUp  = (MTOK / BM) * (DFF / BN);   // 2208

    k_embed<<<dim3(PP, CC), 256, 0, stream>>>(x, pm, emb, h);

    for (int i = 0; i < NBLK; ++i) {
        // ---- row attention (along C) ----
        k_ln<<<MTOK, 256, 0, stream>>>(h, zb, ln1g + i * HH, ln1b + i * HH);
        k_mgemm<false,false,false,false,true><<<gQKV, 256, 0, stream>>>(
            zb, wqkvr_t + (size_t)i * QKVS, nullptr, nullptr, qkvb, MTOK, 768, HH);
        k_fattn<2><<<dim3(PP, NHEAD), 256, 0, stream>>>(
            qkvb, qkvb + 256, qkvb + 512, zb, CC, CC, 1, 768);
        k_mgemm<false,false,true,true,false><<<gO, 256, 0, stream>>>(
            zb, wor_t + (size_t)i * HH * HH, nullptr, h, nullptr, MTOK, HH, HH);
        // ---- column attention (along P) ----
        k_ln<<<MTOK, 256, 0, stream>>>(h, zb, ln2g + i * HH, ln2b + i * HH);
        k_mgemm<false,false,false,false,true><<<gQKV, 256, 0, stream>>>(
            zb, wqkvc_t + (size_t)i * QKVS, nullptr, nullptr, qkvb, MTOK, 768, HH);
        k_fattn<6><<<dim3(CC, NHEAD), 192, 0, stream>>>(
            qkvb, qkvb + 256, qkvb + 512, zb, PP, 1, CC, 768);
        k_mgemm<false,false,true,true,false><<<gO, 256, 0, stream>>>(
            zb, woc_t + (size_t)i * HH * HH, nullptr, h, nullptr, MTOK, HH, HH);
        // ---- feed-forward ----
        k_ln<<<MTOK, 256, 0, stream>>>(h, zb, ln3g + i * HH, ln3b + i * HH);
        k_mgemm<true,true,false,false,true><<<gUp, 256, 0, stream>>>(
            zb, fw1t + (size_t)i * HH * DFF, fb1 + i * DFF, nullptr, bigb, MTOK, DFF, HH);
        if (i == NBLK - 1)
            k_mgemm<true,false,true,true,true><<<gO, 256, 0, stream>>>(
                bigb, fw2t + (size_t)i * HH * DFF, fb2 + i * HH, h, hb, MTOK, HH, DFF);
        else
            k_mgemm<true,false,true,true,false><<<gO, 256, 0, stream>>>(
                bigb, fw2t + (size_t)i * HH * DFF, fb2 + i * HH, h, nullptr, MTOK, HH, DFF);
    }

    // ---- output head ----
    k_mgemm<true,true,false,false,true><<<gUp, 256, 0, stream>>>(
        hb, pw1t, pb1, nullptr, bigb, MTOK, DFF, HH);
    k_head1<<<MTOK, 256, 0, stream>>>(bigb, pw2, pb2, yb);
    k_head2<<<PP, 128, 0, stream>>>(yb, uw, ub, out);
}

// Round 6
// 752.733 us; speedup vs baseline: 6.7909x; 1.1480x over previous
//
#include <hip/hip_runtime.h>
#include <math.h>

#define HH    256
#define NHEAD 8
#define HD    32
#define CC    128
#define RR    24
#define PP    276
#define NBLK  2
#define DFF   1024
#define MTOK  (PP*CC)   // 35328

typedef float          f32x4  __attribute__((ext_vector_type(4)));
typedef short          bf16x8 __attribute__((ext_vector_type(8)));
typedef unsigned short u16;

__device__ __forceinline__ float gelu_f(float x) {
    return 0.5f * x * (1.0f + erff(x * 0.7071067811865476f));
}
__device__ __forceinline__ u16 f2b(float f) {
    unsigned u = __builtin_bit_cast(unsigned, f);
    unsigned r = (u + 0x7fffu + ((u >> 16) & 1u)) >> 16;
    return (u16)r;
}
__device__ __forceinline__ float b2f(u16 b) {
    unsigned u = ((unsigned)b) << 16;
    return __builtin_bit_cast(float, u);
}
__device__ __forceinline__ unsigned cvt_pk_bf16(float lo, float hi) {
    unsigned r;
    asm("v_cvt_pk_bf16_f32 %0, %1, %2" : "=v"(r) : "v"(lo), "v"(hi));
    return r;
}
// async global->LDS, 16B per lane; LDS dest = wave-uniform base + lane*16
__device__ __forceinline__ void gload16(const void* g, void* l) {
    __builtin_amdgcn_global_load_lds(
        (const __attribute__((address_space(1))) unsigned int*)g,
        (__attribute__((address_space(3))) unsigned int*)l, 16, 0, 0);
}

// ---------------------------------------------------------------------------
// h[p,c,:] = sum_r pm[p,r] * emb[x[r,c]]
// ---------------------------------------------------------------------------
__global__ __launch_bounds__(256) void k_embed(
    const int* __restrict__ x, const float* __restrict__ pm,
    const float* __restrict__ emb, float* __restrict__ h) {
    const int p = blockIdx.x, c = blockIdx.y, t = threadIdx.x;
    float acc = 0.f;
    for (int r = 0; r < RR; ++r) {
        float w = pm[p * RR + r];
        if (w != 0.f) {
            int tok = x[r * CC + c];
            acc += w * emb[(size_t)tok * HH + t];
        }
    }
    h[((size_t)p * CC + c) * HH + t] = acc;
}

// ---------------------------------------------------------------------------
// LayerNorm over H=256, bf16 out. Wave per row, float4 loads, 8 rows/block.
// grid = MTOK/8.
// ---------------------------------------------------------------------------
__global__ __launch_bounds__(256) void k_ln(
    const float* __restrict__ in, u16* __restrict__ out,
    const float* __restrict__ g, const float* __restrict__ b) {
    const int lane = threadIdx.x & 63, wid = threadIdx.x >> 6;
    const float4 gv = *(const float4*)&g[lane * 4];
    const float4 bv = *(const float4*)&b[lane * 4];
    #pragma unroll
    for (int rr = 0; rr < 2; ++rr) {
        const int row = blockIdx.x * 8 + wid * 2 + rr;
        const float4 v = *(const float4*)&in[(size_t)row * HH + lane * 4];
        float s  = v.x + v.y + v.z + v.w;
        float s2 = v.x * v.x + v.y * v.y + v.z * v.z + v.w * v.w;
        #pragma unroll
        for (int off = 32; off; off >>= 1) {
            s  += __shfl_xor(s,  off);
            s2 += __shfl_xor(s2, off);
        }
        const float mean = s * (1.f / HH);
        const float rstd = rsqrtf(s2 * (1.f / HH) - mean * mean + 1e-5f);
        const float o0 = (v.x - mean) * rstd * gv.x + bv.x;
        const float o1 = (v.y - mean) * rstd * gv.y + bv.y;
        const float o2 = (v.z - mean) * rstd * gv.z + bv.z;
        const float o3 = (v.w - mean) * rstd * gv.w + bv.w;
        uint2 o;
        o.x = cvt_pk_bf16(o0, o1);
        o.y = cvt_pk_bf16(o2, o3);
        *(uint2*)&out[(size_t)row * HH + lane * 4] = o;
    }
}

// ---------------------------------------------------------------------------
// Transpose + f32->bf16 (+scale): src f32 [R][Cc] -> dst bf16 [Cc][R]
// ---------------------------------------------------------------------------
__global__ __launch_bounds__(256) void k_cvtT(
    const float* __restrict__ src, u16* __restrict__ dst,
    int R, int Cc, int dstStride, float mul) {
    __shared__ float tile[32][33];
    const size_t so = (size_t)blockIdx.z * R * Cc;
    const size_t dOff = (size_t)blockIdx.z * dstStride;
    const int r0 = blockIdx.x * 32, c0 = blockIdx.y * 32;
    const int tx = threadIdx.x & 31, ty = threadIdx.x >> 5;  // 32 x 8
    #pragma unroll
    for (int i = 0; i < 4; ++i)
        tile[ty + 8 * i][tx] = src[so + (size_t)(r0 + ty + 8 * i) * Cc + c0 + tx];
    __syncthreads();
    #pragma unroll
    for (int i = 0; i < 4; ++i)
        dst[dOff + (size_t)(c0 + ty + 8 * i) * R + r0 + tx] = f2b(mul * tile[tx][ty + 8 * i]);
}

// ---------------------------------------------------------------------------
// bf16 MFMA GEMM: C = [C +] act(A[M,K] @ Wt[N,K]^T [+ bias])
// 128x128 tile, BK=32, 4 waves. 3-stage global_load_lds pipeline with
// counted vmcnt (T4): tile t+1/t+2 loads stay in flight across the barrier.
// Swapped-operand MFMA -> per-lane 4 consecutive C columns -> vector stores.
// 1-D grid, XCD-chunked swizzle (nwg % 8 == 0).
// ---------------------------------------------------------------------------
#define BM 128
#define BN 128
#define BK 32
template<bool BIAS, bool GELU, bool RES, bool OF32, bool OBF16>
__global__ __launch_bounds__(256) void k_mgemm(
    const u16* __restrict__ A,   // [M][K] bf16
    const u16* __restrict__ Wt,  // [N][K] bf16 (pre-transposed)
    const float* __restrict__ bias,
    float* __restrict__ C,       // [M][N] f32
    u16* __restrict__ Cb,        // [M][N] bf16 mirror
    int M, int N, int K) {
    __shared__ __align__(16) u16 Al[3][BM * BK];
    __shared__ __align__(16) u16 Bl[3][BN * BK];
    const int tid = threadIdx.x;
    const int wid = tid >> 6, lane = tid & 63;
    const int wr = wid >> 1, wc = wid & 1;
    const int l16 = lane & 15, lh = lane >> 4;

    const int nwg = gridDim.x;
    const int ntx = N >> 7;
    const int swz = (blockIdx.x & 7) * (nwg >> 3) + (blockIdx.x >> 3);
    const int row0 = (swz / ntx) * BM, col0 = (swz % ntx) * BN;

    // stage mapping: dest chunk d -> logical (row r, k-part p), involutory swz
    int rS[2], pS[2];
    #pragma unroll
    for (int i = 0; i < 2; ++i) {
        const int d = tid + i * 256;
        rS[i] = d >> 2;
        pS[i] = (d & 3) ^ ((rS[i] >> 1) & 3);
    }
    const int nt = K / BK;

    auto stage = [&](int buf, int kt) {
        #pragma unroll
        for (int i = 0; i < 2; ++i) {
            gload16(A  + (size_t)(row0 + rS[i]) * K + kt + pS[i] * 8,
                    (char*)&Al[buf][0] + (wid * 64 + i * 256) * 16);
            gload16(Wt + (size_t)(col0 + rS[i]) * K + kt + pS[i] * 8,
                    (char*)&Bl[buf][0] + (wid * 64 + i * 256) * 16);
        }
    };

    f32x4 acc[4][4];
    #pragma unroll
    for (int m = 0; m < 4; ++m)
        #pragma unroll
        for (int n = 0; n < 4; ++n) acc[m][n] = (f32x4){0.f, 0.f, 0.f, 0.f};

    stage(0, 0);            // 4 loads/thread
    stage(1, BK);           // 4 more -> 8 outstanding
    for (int t = 0; t < nt; ++t) {
        const int cur = t % 3;
        // wait for tile t's 4 loads (tile t+1's stay in flight)
        if (t + 1 < nt) asm volatile("s_waitcnt vmcnt(4)" ::: "memory");
        else            asm volatile("s_waitcnt vmcnt(0)" ::: "memory");
        __builtin_amdgcn_s_barrier();
        __builtin_amdgcn_sched_barrier(0);
        if (t + 2 < nt) stage((t + 2) % 3, (t + 2) * BK);
        bf16x8 af[4], bfr[4];
        #pragma unroll
        for (int m = 0; m < 4; ++m) {
            const int r = wr * 64 + m * 16 + l16;
            af[m] = *(const bf16x8*)((const char*)&Al[cur][0]
                     + r * 64 + ((lh ^ ((r >> 1) & 3)) << 4));
        }
        #pragma unroll
        for (int n = 0; n < 4; ++n) {
            const int nn = wc * 64 + n * 16 + l16;
            bfr[n] = *(const bf16x8*)((const char*)&Bl[cur][0]
                     + nn * 64 + ((lh ^ ((nn >> 1) & 3)) << 4));
        }
        asm volatile("s_waitcnt lgkmcnt(0)" ::: "memory");
        __builtin_amdgcn_sched_barrier(0);
        // swapped operands: D[lane] = C[row=m*16+l16][cols n*16+lh*4 .. +3]
        #pragma unroll
        for (int m = 0; m < 4; ++m)
            #pragma unroll
            for (int n = 0; n < 4; ++n)
                acc[m][n] = __builtin_amdgcn_mfma_f32_16x16x32_bf16(
                    bfr[n], af[m], acc[m][n], 0, 0, 0);
    }
    // epilogue: per (m,n): row = row0+wr*64+m*16+l16, 4 consecutive cols
    const int lh4 = lh * 4;
    #pragma unroll
    for (int m = 0; m < 4; ++m) {
        const int rowg = row0 + wr * 64 + m * 16 + l16;
        #pragma unroll
        for (int n = 0; n < 4; ++n) {
            const int colg = col0 + wc * 64 + n * 16 + lh4;
            const size_t off = (size_t)rowg * N + colg;
            f32x4 v = acc[m][n];
            if (BIAS) {
                const f32x4 bv = *(const f32x4*)&bias[colg];
                v += bv;
            }
            if (GELU) {
                v[0] = gelu_f(v[0]); v[1] = gelu_f(v[1]);
                v[2] = gelu_f(v[2]); v[3] = gelu_f(v[3]);
            }
            if (RES) v += *(const f32x4*)&C[off];
            if (OF32) *(f32x4*)&C[off] = v;
            if (OBF16) {
                uint2 o;
                o.x = cvt_pk_bf16(v[0], v[1]);
                o.y = cvt_pk_bf16(v[2], v[3]);
                *(uint2*)&Cb[off] = o;
            }
        }
    }
}

// ---------------------------------------------------------------------------
// Fused MFMA flash attention (bf16 in/out, f32 softmax state).
// ---------------------------------------------------------------------------
template<int NQT>
__global__ __launch_bounds__(256) void k_fattn(
    const u16* __restrict__ qg, const u16* __restrict__ kg,
    const u16* __restrict__ vg, u16* __restrict__ og,
    int S, int base_mul, int stride, int rowH) {
    const int head = blockIdx.y;
    const int base = blockIdx.x * base_mul;
    const int tid  = threadIdx.x;
    const int w = tid >> 6, lane = tid & 63;
    const int l16 = lane & 15, lh = lane >> 4;

    __shared__ u16 Vt[32 * 296];           // [d][key], stride 296 elems

    const int nkt = (S + 15) >> 4;
    const int nch = (nkt + 1) >> 1;
    const int KP  = nch * 32;

    for (int it = tid; it < KP * 4; it += blockDim.x) {
        const int key = it >> 2, d8 = (it & 3) * 8;
        uint4 t4 = make_uint4(0u, 0u, 0u, 0u);
        if (key < S)
            t4 = *(const uint4*)(vg + (size_t)(base + key * stride) * rowH + head * HD + d8);
        Vt[(d8 + 0) * 296 + key] = (u16)(t4.x);
        Vt[(d8 + 1) * 296 + key] = (u16)(t4.x >> 16);
        Vt[(d8 + 2) * 296 + key] = (u16)(t4.y);
        Vt[(d8 + 3) * 296 + key] = (u16)(t4.y >> 16);
        Vt[(d8 + 4) * 296 + key] = (u16)(t4.z);
        Vt[(d8 + 5) * 296 + key] = (u16)(t4.z >> 16);
        Vt[(d8 + 6) * 296 + key] = (u16)(t4.w);
        Vt[(d8 + 7) * 296 + key] = (u16)(t4.w >> 16);
    }
    __syncthreads();

    bf16x8 qf[NQT];
    #pragma unroll
    for (int j = 0; j < NQT; ++j) {
        int qi = (w * NQT + j) * 16 + l16;
        int qc = qi < S ? qi : S - 1;
        qf[j] = *(const bf16x8*)(qg + (size_t)(base + qc * stride) * rowH + head * HD + lh * 8);
    }
    f32x4 acc[NQT][2];
    float mM[NQT], lL[NQT];
    #pragma unroll
    for (int j = 0; j < NQT; ++j) {
        acc[j][0] = (f32x4){0.f, 0.f, 0.f, 0.f};
        acc[j][1] = (f32x4){0.f, 0.f, 0.f, 0.f};
        mM[j] = -1e30f; lL[j] = 0.f;
    }

    auto ldK = [&](int kid) -> bf16x8 {
        int kc = kid < S ? kid : S - 1;
        return *(const bf16x8*)(kg + (size_t)(base + kc * stride) * rowH + head * HD + lh * 8);
    };
    auto ldV = [&](int ch, int dm) -> bf16x8 {
        return *(const bf16x8*)(Vt + (dm * 16 + l16) * 296 + ch * 32 + lh * 8);
    };

    bf16x8 kc0 = ldK(l16), kc1 = ldK(16 + l16);
    bf16x8 vc0 = ldV(0, 0), vc1 = ldV(0, 1);
    const int g0 = 2 * (lh & 1);
    const int src0 = l16 + 16 * g0, src1 = src0 + 16;
    const bool hiT = (lh >> 1) & 1;
    const int lh4 = lh * 4;

    for (int ch = 0; ch < nch; ++ch) {
        bf16x8 kn0, kn1, vn0, vn1;
        if (ch + 1 < nch) {
            kn0 = ldK((ch + 1) * 32 + l16);
            kn1 = ldK((ch + 1) * 32 + 16 + l16);
            vn0 = ldV(ch + 1, 0);
            vn1 = ldV(ch + 1, 1);
        }
        const int kb = ch * 32;
        const bool fullv = (kb + 32 <= S);
        #pragma unroll
        for (int j = 0; j < NQT; ++j) {
            f32x4 s0 = __builtin_amdgcn_mfma_f32_16x16x32_bf16(
                kc0, qf[j], (f32x4){0.f, 0.f, 0.f, 0.f}, 0, 0, 0);
            f32x4 s1 = __builtin_amdgcn_mfma_f32_16x16x32_bf16(
                kc1, qf[j], (f32x4){0.f, 0.f, 0.f, 0.f}, 0, 0, 0);
            if (!fullv) {
                #pragma unroll
                for (int i = 0; i < 4; ++i) {
                    s0[i] = (kb + lh4 + i      < S) ? s0[i] : -1e30f;
                    s1[i] = (kb + 16 + lh4 + i < S) ? s1[i] : -1e30f;
                }
            }
            float mx = fmaxf(fmaxf(fmaxf(s0[0], s0[1]), fmaxf(s0[2], s0[3])),
                             fmaxf(fmaxf(s1[0], s1[1]), fmaxf(s1[2], s1[3])));
            mx = fmaxf(mx, __shfl_xor(mx, 16));
            mx = fmaxf(mx, __shfl_xor(mx, 32));
            const float mn = fmaxf(mM[j], mx);
            const float corr = __expf(mM[j] - mn);
            mM[j] = mn;
            float p0[4], p1[4], ls = 0.f;
            #pragma unroll
            for (int i = 0; i < 4; ++i) {
                p0[i] = __expf(s0[i] - mn); ls += p0[i];
                p1[i] = __expf(s1[i] - mn); ls += p1[i];
            }
            lL[j] = lL[j] * corr + ls;
            acc[j][0] *= corr;
            acc[j][1] *= corr;
            const int w00 = (int)cvt_pk_bf16(p0[0], p0[1]);
            const int w01 = (int)cvt_pk_bf16(p0[2], p0[3]);
            const int w10 = (int)cvt_pk_bf16(p1[0], p1[1]);
            const int w11 = (int)cvt_pk_bf16(p1[2], p1[3]);
            uint4 W;
            { int a = __shfl(w00, src0), b = __shfl(w10, src0); W.x = (unsigned)(hiT ? b : a); }
            { int a = __shfl(w01, src0), b = __shfl(w11, src0); W.y = (unsigned)(hiT ? b : a); }
            { int a = __shfl(w00, src1), b = __shfl(w10, src1); W.z = (unsigned)(hiT ? b : a); }
            { int a = __shfl(w01, src1), b = __shfl(w11, src1); W.w = (unsigned)(hiT ? b : a); }
            const bf16x8 pw = __builtin_bit_cast(bf16x8, W);
            acc[j][0] = __builtin_amdgcn_mfma_f32_16x16x32_bf16(vc0, pw, acc[j][0], 0, 0, 0);
            acc[j][1] = __builtin_amdgcn_mfma_f32_16x16x32_bf16(vc1, pw, acc[j][1], 0, 0, 0);
        }
        kc0 = kn0; kc1 = kn1; vc0 = vn0; vc1 = vn1;
    }

    #pragma unroll
    for (int j = 0; j < NQT; ++j) {
        float lf = lL[j];
        lf += __shfl_xor(lf, 16);
        lf += __shfl_xor(lf, 32);
        const float inv = 1.f / lf;
        const int qi = (w * NQT + j) * 16 + l16;
        if (qi < S) {
            u16* dst = og + (size_t)(base + qi * stride) * HH + head * HD + lh4;
            #pragma unroll
            for (int dm = 0; dm < 2; ++dm) {
                uint2 o2;
                o2.x = cvt_pk_bf16(acc[j][dm][0] * inv, acc[j][dm][1] * inv);
                o2.y = cvt_pk_bf16(acc[j][dm][2] * inv, acc[j][dm][3] * inv);
                *(uint2*)(dst + dm * 16) = o2;
            }
        }
    }
}

// ---------------------------------------------------------------------------
__global__ __launch_bounds__(256) void k_head1(
    const u16* __restrict__ g, const float* __restrict__ pw2,
    const float* __restrict__ pb2, float* __restrict__ y) {
    const int tok = blockIdx.x, t = threadIdx.x;
    const ushort4 r4 = *(const ushort4*)&g[(size_t)tok * DFF + t * 4];
    const float4  w4 = *(const float4*)&pw2[t * 4];
    float s = b2f(r4.x) * w4.x + b2f(r4.y) * w4.y
            + b2f(r4.z) * w4.z + b2f(r4.w) * w4.w;
    #pragma unroll
    for (int off = 32; off; off >>= 1) s += __shfl_down(s, off);
    __shared__ float sm[4];
    if ((t & 63) == 0) sm[t >> 6] = s;
    __syncthreads();
    if (t == 0) y[tok] = sm[0] + sm[1] + sm[2] + sm[3] + pb2[0];
}

__global__ __launch_bounds__(128) void k_head2(
    const float* __restrict__ y, const float* __restrict__ uw,
    const float* __restrict__ ub, float* __restrict__ out) {
    const int p = blockIdx.x, t = threadIdx.x;
    float s = y[(size_t)p * CC + t] * uw[t];
    #pragma unroll
    for (int off = 32; off; off >>= 1) s += __shfl_down(s, off);
    __shared__ float sm[2];
    if ((t & 63) == 0) sm[t >> 6] = s;
    __syncthreads();
    if (t == 0) out[p] = sm[0] + sm[1] + ub[0];
}

// ---------------------------------------------------------------------------
extern "C" void kernel_launch(void* const* d_in, const int* in_sizes, int n_in,
                              void* d_out, int out_size, void* d_ws, size_t ws_size,
                              hipStream_t stream) {
    (void)in_sizes; (void)n_in; (void)out_size; (void)ws_size;
    const int*   x    = (const int*)  d_in[0];
    const float* pm   = (const float*)d_in[1];
    const float* emb  = (const float*)d_in[2];
    const float* ln1g = (const float*)d_in[3];
    const float* ln1b = (const float*)d_in[4];
    const float* wqr  = (const float*)d_in[5];
    const float* wkr  = (const float*)d_in[6];
    const float* wvr  = (const float*)d_in[7];
    const float* wor  = (const float*)d_in[8];
    const float* ln2g = (const float*)d_in[9];
    const float* ln2b = (const float*)d_in[10];
    const float* wqc  = (const float*)d_in[11];
    const float* wkc  = (const float*)d_in[12];
    const float* wvc  = (const float*)d_in[13];
    const float* woc  = (const float*)d_in[14];
    const float* ln3g = (const float*)d_in[15];
    const float* ln3b = (const float*)d_in[16];
    const float* fw1  = (const float*)d_in[17];
    const float* fb1  = (const float*)d_in[18];
    const float* fw2  = (const float*)d_in[19];
    const float* fb2  = (const float*)d_in[20];
    const float* pw1  = (const float*)d_in[21];
    const float* pb1  = (const float*)d_in[22];
    const float* pw2  = (const float*)d_in[23];
    const float* pb2  = (const float*)d_in[24];
    const float* uw   = (const float*)d_in[25];
    const float* ub   = (const float*)d_in[26];
    float* out = (float*)d_out;

    // ---- workspace layout ----
    char* wsp = (char*)d_ws;
    float* h   = (float*)wsp;                              // 36,175,872 B
    u16*   zb  = (u16*)(wsp + 36175872);                   // 18,087,936 B
    u16*   hb  = zb + (size_t)MTOK * HH;                   // 18,087,936 B
    u16*   wts = hb + (size_t)MTOK * HH;                   //  4,718,592 B
    float* yb  = (float*)((char*)wts + 4718592);           //    141,312 B
    u16*   scratch = (u16*)((char*)yb + 141312);
    u16* qkvb = scratch;                                   // [MTOK][768] bf16 (54 MB)
    u16* bigb = scratch;                                   // [MTOK][1024] bf16 (72 MB), aliased

    u16* wqkvr_t = wts;                                    // 2 x [768][256]
    u16* wqkvc_t = wqkvr_t + 2 * 768 * HH;                 // 2 x [768][256]
    u16* wor_t   = wqkvc_t + 2 * 768 * HH;                 // 2 x [256][256]
    u16* woc_t   = wor_t + 2 * HH * HH;
    u16* fw1t    = woc_t + 2 * HH * HH;                    // 2 x [1024][256]
    u16* fw2t    = fw1t + 2 * HH * DFF;                    // 2 x [256][1024]
    u16* pw1t    = fw2t + 2 * HH * DFF;                    // [1024][256]

    const float qscale = 0.17677669529663687f;   // 1/sqrt(32), folded into wq
    const int QKVS = 768 * HH;

    k_cvtT<<<dim3(8, 8, 2),  256, 0, stream>>>(wqr, wqkvr_t,            HH, HH, QKVS, qscale);
    k_cvtT<<<dim3(8, 8, 2),  256, 0, stream>>>(wkr, wqkvr_t + 256 * HH, HH, HH, QKVS, 1.f);
    k_cvtT<<<dim3(8, 8, 2),  256, 0, stream>>>(wvr, wqkvr_t + 512 * HH, HH, HH, QKVS, 1.f);
    k_cvtT<<<dim3(8, 8, 2),  256, 0, stream>>>(wqc, wqkvc_t,            HH, HH, QKVS, qscale);
    k_cvtT<<<dim3(8, 8, 2),  256, 0, stream>>>(wkc, wqkvc_t + 256 * HH, HH, HH, QKVS, 1.f);
    k_cvtT<<<dim3(8, 8, 2),  256, 0, stream>>>(wvc, wqkvc_t + 512 * HH, HH, HH, QKVS, 1.f);
    k_cvtT<<<dim3(8, 8, 2),  256, 0, stream>>>(wor, wor_t, HH, HH, HH * HH, 1.f);
    k_cvtT<<<dim3(8, 8, 2),  256, 0, stream>>>(woc, woc_t, HH, HH, HH * HH, 1.f);
    k_cvtT<<<dim3(8, 32, 2), 256, 0, stream>>>(fw1, fw1t, HH, DFF, HH * DFF, 1.f);
    k_cvtT<<<dim3(32, 8, 2), 256, 0, stream>>>(fw2, fw2t, DFF, HH, HH * DFF, 1.f);
    k_cvtT<<<dim3(8, 32, 1), 256, 0, stream>>>(pw1, pw1t, HH, DFF, 0, 1.f);

    const int gQKV = (MTOK / BM) * (768 / BN);   // 1656
    const int gO   = (MTOK / BM) * (HH  / BN);   // 552
    const int gUp  = (MTOK / BM) * (DFF / BN);   // 2208

    k_embed<<<dim3(PP, CC), 256, 0, stream>>>(x, pm, emb, h);

    for (int i = 0; i < NBLK; ++i) {
        // ---- row attention (along C) ----
        k_ln<<<MTOK / 8, 256, 0, stream>>>(h, zb, ln1g + i * HH, ln1b + i * HH);
        k_mgemm<false,false,false,false,true><<<gQKV, 256, 0, stream>>>(
            zb, wqkvr_t + (size_t)i * QKVS, nullptr, nullptr, qkvb, MTOK, 768, HH);
        k_fattn<2><<<dim3(PP, NHEAD), 256, 0, stream>>>(
            qkvb, qkvb + 256, qkvb + 512, zb, CC, CC, 1, 768);
        k_mgemm<false,false,true,true,false><<<gO, 256, 0, stream>>>(
            zb, wor_t + (size_t)i * HH * HH, nullptr, h, nullptr, MTOK, HH, HH);
        // ---- column attention (along P) ----
        k_ln<<<MTOK / 8, 256, 0, stream>>>(h, zb, ln2g + i * HH, ln2b + i * HH);
        k_mgemm<false,false,false,false,true><<<gQKV, 256, 0, stream>>>(
            zb, wqkvc_t + (size_t)i * QKVS, nullptr, nullptr, qkvb, MTOK, 768, HH);
        k_fattn<6><<<dim3(CC, NHEAD), 192, 0, stream>>>(
            qkvb, qkvb + 256, qkvb + 512, zb, PP, 1, CC, 768);
        k_mgemm<false,false,true,true,false><<<gO, 256, 0, stream>>>(
            zb, woc_t + (size_t)i * HH * HH, nullptr, h, nullptr, MTOK, HH, HH);
        // ---- feed-forward ----
        k_ln<<<MTOK / 8, 256, 0, stream>>>(h, zb, ln3g + i * HH, ln3b + i * HH);
        k_mgemm<true,true,false,false,true><<<gUp, 256, 0, stream>>>(
            zb, fw1t + (size_t)i * HH * DFF, fb1 + i * DFF, nullptr, bigb, MTOK, DFF, HH);
        if (i == NBLK - 1)
            k_mgemm<true,false,true,true,true><<<gO, 256, 0, stream>>>(
                bigb, fw2t + (size_t)i * HH * DFF, fb2 + i * HH, h, hb, MTOK, HH, DFF);
        else
            k_mgemm<true,false,true,true,false><<<gO, 256, 0, stream>>>(
                bigb, fw2t + (size_t)i * HH * DFF, fb2 + i * HH, h, nullptr, MTOK, HH, DFF);
    }

    // ---- output head ----
    k_mgemm<true,true,false,false,true><<<gUp, 256, 0, stream>>>(
        hb, pw1t, pb1, nullptr, bigb, MTOK, DFF, HH);
    k_head1<<<MTOK, 256, 0, stream>>>(bigb, pw2, pb2, yb);
    k_head2<<<PP, 128, 0, stream>>>(yb, uw, ub, out);
}